// Round 7
// baseline (1931.263 us; speedup 1.0000x reference)
//
#include <hip/hip_runtime.h>
#include <hip/hip_bf16.h>
#include <math.h>

// Problem constants (from reference)
#define B_SZ   128
#define HDIM   256
#define NG     1280     // 5*H
#define NNODES 1023
#define VOCAB  2048
#define NBLK   512      // persistent grid: 2 blocks/CU x 256 CUs, guaranteed
                        // co-resident by __launch_bounds__(256,2) + 32KB LDS

typedef unsigned int uint32;
typedef short  short8v  __attribute__((ext_vector_type(8)));   // 8 x bf16 (4 VGPR)
typedef float  float4v  __attribute__((ext_vector_type(4)));   // MFMA C/D frag

#if __has_builtin(__builtin_amdgcn_rcpf)
#define FRCP(x) __builtin_amdgcn_rcpf(x)
#else
#define FRCP(x) (1.0f / (x))
#endif
#if __has_builtin(__builtin_amdgcn_exp2f)
#define FEXP2(x) __builtin_amdgcn_exp2f(x)
#else
#define FEXP2(x) exp2f(x)
#endif

__device__ __forceinline__ float sigm(float x) {
    return FRCP(1.0f + FEXP2(-1.44269504f * x));    // native v_rcp/v_exp, no Newton
}
__device__ __forceinline__ float tanh_fast(float x) {
    return 2.0f * FRCP(1.0f + FEXP2(-2.88539008f * x)) - 1.0f;
}
__device__ __forceinline__ float bf2f(unsigned short u) {
    return __uint_as_float(((uint32)u) << 16);
}
__device__ __forceinline__ unsigned short f2bf(float f) {
    uint32 x = __float_as_uint(f);
    uint32 r = (x + 0x7FFFu + ((x >> 16) & 1u)) >> 16;   // RNE
    return (unsigned short)r;
}

// ---------------------------------------------------------------------------
// embb = bf16(emb) : 2048 x 256.  1 MB table -> L2-resident gather target.
// ---------------------------------------------------------------------------
__global__ __launch_bounds__(256) void embb_kernel(
    const float* __restrict__ emb, unsigned short* __restrict__ embb)
{
    const int t = blockIdx.x * 256 + threadIdx.x;
    const float4 v0 = *(const float4*)(emb + (size_t)t * 8);
    const float4 v1 = *(const float4*)(emb + (size_t)t * 8 + 4);
    short8v o;
    o[0] = (short)f2bf(v0.x); o[1] = (short)f2bf(v0.y);
    o[2] = (short)f2bf(v0.z); o[3] = (short)f2bf(v0.w);
    o[4] = (short)f2bf(v1.x); o[5] = (short)f2bf(v1.y);
    o[6] = (short)f2bf(v1.z); o[7] = (short)f2bf(v1.w);
    *(short8v*)(embb + (size_t)t * 8) = o;
}

// ---------------------------------------------------------------------------
// WTf: fragment-ready bf16 repack of [Ul;Ur;Wx] (K=768, N=1280) for MFMA B.
// short8 index = (ng*24 + ks)*64 + lane ; lane = q*16 + c
//   holds B[k = ks*32 + q*8 + j][col = ng*16 + c],  j = 0..7
// ---------------------------------------------------------------------------
__global__ __launch_bounds__(256) void prep_wtf(
    const float* __restrict__ Ul, const float* __restrict__ Ur,
    const float* __restrict__ Wx, unsigned short* __restrict__ WTf)
{
    const int t = blockIdx.x * 256 + threadIdx.x;   // 0..122879
    const int l = t & 63;
    const int q = l >> 4, c = l & 15;
    const int ks = (t >> 6) % 24;
    const int ng = t / (24 * 64);                    // 0..79
    const int col = ng * 16 + c;
    const int k = ks * 32 + q * 8;
    const float* src = (k < 256) ? (Ul + (size_t)k * NG + col)
                     : (k < 512) ? (Ur + (size_t)(k - 256) * NG + col)
                                 : (Wx + (size_t)(k - 512) * NG + col);
    short8v v;
    #pragma unroll
    for (int j = 0; j < 8; ++j) v[j] = (short)f2bf(src[(size_t)j * NG]);
    *(short8v*)(WTf + (size_t)t * 8) = v;
}

// ---------------------------------------------------------------------------
// Software grid barrier (all NBLK blocks co-resident by construction).
// Bounded spin: a failure shows up as wrong absmax, not a hang.
// ---------------------------------------------------------------------------
__device__ __forceinline__ void grid_sync(uint32* bar) {
    __syncthreads();
    if (threadIdx.x == 0) {
        const uint32 gen = __hip_atomic_load(&bar[1], __ATOMIC_RELAXED, __HIP_MEMORY_SCOPE_AGENT);
        __threadfence();
        const uint32 a = __hip_atomic_fetch_add(&bar[0], 1u, __ATOMIC_ACQ_REL, __HIP_MEMORY_SCOPE_AGENT);
        if (a == (uint32)gridDim.x - 1u) {
            __hip_atomic_store(&bar[0], 0u, __ATOMIC_RELAXED, __HIP_MEMORY_SCOPE_AGENT);
            __hip_atomic_fetch_add(&bar[1], 1u, __ATOMIC_RELEASE, __HIP_MEMORY_SCOPE_AGENT);
        } else {
            long spin = 0;
            while (__hip_atomic_load(&bar[1], __ATOMIC_ACQUIRE, __HIP_MEMORY_SCOPE_AGENT) == gen
                   && spin < 200000000L) ++spin;
        }
        __threadfence();
    }
    __syncthreads();
}

// ---------------------------------------------------------------------------
// One 64-row x 64-col x 5-gate inner tile (levels d=8..0).  K=768 MFMA with
// depth-3 A / depth-2 B register pipeline (covers L2-class latency; round-6
// postmortem: dist-1 left ~700 cyc of HBM/L3 latency exposed per K-step).
// ---------------------------------------------------------------------------
__device__ __forceinline__ void inner_tile(
    const int d, const int n, const int rowBase, const int jtile,
    const short8v* __restrict__ WTfv, const unsigned short* __restrict__ embb,
    const float* __restrict__ bias, const int* __restrict__ tokens,
    const unsigned short* __restrict__ hsrc, const unsigned short* __restrict__ csrc,
    unsigned short* __restrict__ hdst, unsigned short* __restrict__ cdst,
    float* __restrict__ out, unsigned short* cst, unsigned short* wb,
    const int tid, const int lane, const int w, const int quad, const int col15)
{
    const int jbase = jtile * 64;

    const unsigned short* chp[4];
    const unsigned short* xp[4];
    #pragma unroll
    for (int rt = 0; rt < 4; ++rt) {
        const int row = rowBase + rt * 16 + col15;
        const int b = row >> d, i = row & (n - 1);
        chp[rt] = hsrc + (size_t)(2 * row) * HDIM + quad * 8;
        const int tok = tokens[b * NNODES + (n - 1) + i];
        xp[rt] = embb + (size_t)tok * HDIM + quad * 8;
    }
    const short8v* bp[5];
    #pragma unroll
    for (int g = 0; g < 5; ++g)
        bp[g] = WTfv + ((size_t)(g * 16 + jtile * 4 + w) * 24) * 64 + lane;

    float4v acc[4][5];
    #pragma unroll
    for (int rt = 0; rt < 4; ++rt)
        #pragma unroll
        for (int g = 0; g < 5; ++g)
            #pragma unroll
            for (int e = 0; e < 4; ++e) acc[rt][g][e] = 0.0f;

    short8v ab[3][4], bb[2][5];
    #pragma unroll
    for (int rt = 0; rt < 4; ++rt) {
        ab[0][rt] = *(const short8v*)(chp[rt]);
        ab[1][rt] = *(const short8v*)(chp[rt] + 32);
    }
    #pragma unroll
    for (int g = 0; g < 5; ++g) bb[0][g] = bp[g][0];

    #pragma unroll
    for (int ks = 0; ks < 24; ++ks) {
        if (ks < 22) {
            const int kn = ks + 2;
            #pragma unroll
            for (int rt = 0; rt < 4; ++rt) {
                const unsigned short* p =
                    (kn < 8)  ? (chp[rt] + kn * 32)
                  : (kn < 16) ? (chp[rt] + HDIM + (kn - 8) * 32)
                              : (xp[rt] + (kn - 16) * 32);
                ab[kn % 3][rt] = *(const short8v*)p;
            }
        }
        if (ks < 23) {
            #pragma unroll
            for (int g = 0; g < 5; ++g) bb[(ks + 1) & 1][g] = bp[g][(size_t)(ks + 1) * 64];
        }
        #pragma unroll
        for (int rt = 0; rt < 4; ++rt)
            #pragma unroll
            for (int g = 0; g < 5; ++g)
                acc[rt][g] = __builtin_amdgcn_mfma_f32_16x16x32_bf16(
                    ab[ks % 3][rt], bb[ks & 1][g], acc[rt][g], 0, 0, 0);
    }

    // Stage child c (contiguous rows 2*rowBase..+128), swizzled
    #pragma unroll
    for (int k2 = 0; k2 < 4; ++k2) {
        const int c = tid + k2 * 256;
        const int rr = c >> 4, side = (c >> 3) & 1, u = c & 7;
        const short8v v = *(const short8v*)(csrc +
            (size_t)(2 * (rowBase + rr) + side) * HDIM + jbase + u * 8);
        const int ru = (u + 2 * ((rr >> 2) & 3)) & 7;
        *(short8v*)(cst + (rr * 128 + side * 64 + ru * 8)) = v;
    }
    __syncthreads();

    // Cell math (C layout: col=lane&15, row=quad*4+reg — verified m89)
    const int jl = w * 16 + col15;
    const int j  = jbase + jl;
    const float b_i  = bias[j],       b_fl = bias[256 + j], b_fr = bias[512 + j];
    const float b_o  = bias[768 + j], b_u  = bias[1024 + j];
    const int jchunk = jl >> 3, jpos = jl & 7;
    float hv[4][4], cv[4][4];
    #pragma unroll
    for (int rt = 0; rt < 4; ++rt) {
        #pragma unroll
        for (int reg = 0; reg < 4; ++reg) {
            const int rr = rt * 16 + quad * 4 + reg;
            const int roff = ((jchunk + 2 * quad) & 7) * 8 + jpos;
            const float gi  = acc[rt][0][reg] + b_i;
            const float gfl = acc[rt][1][reg] + b_fl;
            const float gfr = acc[rt][2][reg] + b_fr;
            const float go  = acc[rt][3][reg] + b_o;
            const float gu  = acc[rt][4][reg] + b_u;
            const float cl  = bf2f(cst[rr * 128 +      roff]);
            const float cr  = bf2f(cst[rr * 128 + 64 + roff]);
            const float ii = sigm(gi), fl = sigm(gfl), fr = sigm(gfr), oo = sigm(go);
            const float uu = tanh_fast(gu);
            const float c = ii * uu + fl * cl + fr * cr;
            const float h = oo * tanh_fast(c);
            cv[rt][reg] = c; hv[rt][reg] = h;
            if (d == 0) out[(size_t)(rowBase + rr) * HDIM + j] = h;
        }
    }
    __syncthreads();

    #pragma unroll
    for (int rt = 0; rt < 4; ++rt) {
        #pragma unroll
        for (int reg = 0; reg < 4; ++reg) {
            const int rr = rt * 16 + quad * 4 + reg;
            const int roff = ((jchunk + 2 * quad) & 7) * 8 + jpos;
            wb[rr * 64 + roff]        = f2bf(hv[rt][reg]);
            wb[4096 + rr * 64 + roff] = f2bf(cv[rt][reg]);
        }
    }
    __syncthreads();

    #pragma unroll
    for (int k2 = 0; k2 < 4; ++k2) {
        const int c = tid + k2 * 256;
        const int arr = c >> 9, rr = (c >> 3) & 63, u = c & 7;
        const int ru = (u + 2 * ((rr >> 2) & 3)) & 7;
        const short8v v = *(const short8v*)(wb + (arr * 4096 + rr * 64 + ru * 8));
        unsigned short* dstp = (arr ? cdst : hdst) +
            (size_t)(rowBase + rr) * HDIM + jbase + u * 8;
        *(short8v*)dstp = v;
    }
}

// ---------------------------------------------------------------------------
// Leaf tile (d=9): gates {i,o,u} = x @ Wx + b, x = embb[tok]; K=256.
// ---------------------------------------------------------------------------
__device__ __forceinline__ void leaf_tile(
    const int rowBase, const int jtile,
    const short8v* __restrict__ WTfv, const unsigned short* __restrict__ embb,
    const float* __restrict__ bias, const int* __restrict__ tokens,
    unsigned short* __restrict__ hdst, unsigned short* __restrict__ cdst,
    unsigned short* wb,
    const int tid, const int lane, const int w, const int quad, const int col15)
{
    const int jbase = jtile * 64;
    const unsigned short* xp[4];
    #pragma unroll
    for (int rt = 0; rt < 4; ++rt) {
        const int row = rowBase + rt * 16 + col15;
        const int b = row >> 9, i = row & 511;
        const int tok = tokens[b * NNODES + 511 + i];
        xp[rt] = embb + (size_t)tok * HDIM + quad * 8;
    }
    const short8v* bp[3];
    bp[0] = WTfv + ((size_t)(0 * 16 + jtile * 4 + w) * 24 + 16) * 64 + lane;
    bp[1] = WTfv + ((size_t)(3 * 16 + jtile * 4 + w) * 24 + 16) * 64 + lane;
    bp[2] = WTfv + ((size_t)(4 * 16 + jtile * 4 + w) * 24 + 16) * 64 + lane;

    float4v acc[4][3];
    #pragma unroll
    for (int rt = 0; rt < 4; ++rt)
        #pragma unroll
        for (int gi = 0; gi < 3; ++gi)
            #pragma unroll
            for (int e = 0; e < 4; ++e) acc[rt][gi][e] = 0.0f;

    short8v ab[3][4], bb[2][3];
    #pragma unroll
    for (int rt = 0; rt < 4; ++rt) {
        ab[0][rt] = *(const short8v*)(xp[rt]);
        ab[1][rt] = *(const short8v*)(xp[rt] + 32);
    }
    #pragma unroll
    for (int gi = 0; gi < 3; ++gi) bb[0][gi] = bp[gi][0];

    #pragma unroll
    for (int ks = 0; ks < 8; ++ks) {
        if (ks < 6) {
            #pragma unroll
            for (int rt = 0; rt < 4; ++rt)
                ab[(ks + 2) % 3][rt] = *(const short8v*)(xp[rt] + (ks + 2) * 32);
        }
        if (ks < 7) {
            #pragma unroll
            for (int gi = 0; gi < 3; ++gi) bb[(ks + 1) & 1][gi] = bp[gi][(size_t)(ks + 1) * 64];
        }
        #pragma unroll
        for (int rt = 0; rt < 4; ++rt)
            #pragma unroll
            for (int gi = 0; gi < 3; ++gi)
                acc[rt][gi] = __builtin_amdgcn_mfma_f32_16x16x32_bf16(
                    ab[ks % 3][rt], bb[ks & 1][gi], acc[rt][gi], 0, 0, 0);
    }

    const int jl = w * 16 + col15;
    const int j  = jbase + jl;
    const float b_i = bias[j], b_o = bias[768 + j], b_u = bias[1024 + j];
    const int jchunk = jl >> 3, jpos = jl & 7;

    __syncthreads();    // wb may still be read by the previous tile's stores
    #pragma unroll
    for (int rt = 0; rt < 4; ++rt) {
        #pragma unroll
        for (int reg = 0; reg < 4; ++reg) {
            const int rr = rt * 16 + quad * 4 + reg;
            const float gi = acc[rt][0][reg] + b_i;
            const float go = acc[rt][1][reg] + b_o;
            const float gu = acc[rt][2][reg] + b_u;
            const float c = sigm(gi) * tanh_fast(gu);
            const float h = sigm(go) * tanh_fast(c);
            const int roff = ((jchunk + 2 * quad) & 7) * 8 + jpos;
            wb[rr * 64 + roff]        = f2bf(h);
            wb[4096 + rr * 64 + roff] = f2bf(c);
        }
    }
    __syncthreads();
    #pragma unroll
    for (int k2 = 0; k2 < 4; ++k2) {
        const int c = tid + k2 * 256;
        const int arr = c >> 9, rr = (c >> 3) & 63, u = c & 7;
        const int ru = (u + 2 * ((rr >> 2) & 3)) & 7;
        const short8v v = *(const short8v*)(wb + (arr * 4096 + rr * 64 + ru * 8));
        unsigned short* dstp = (arr ? cdst : hdst) +
            (size_t)(rowBase + rr) * HDIM + jbase + u * 8;
        *(short8v*)dstp = v;
    }
}

// ---------------------------------------------------------------------------
// Persistent kernel: all 10 levels in one launch, software grid barrier
// between levels.  XCD-affine tile mapping: row-slice s of EVERY level is
// processed by blocks with blockIdx%8==s, so child h/c stay in the producing
// XCD's L2 (parent rows' children land in the same slice).
// ---------------------------------------------------------------------------
__global__ __launch_bounds__(256, 2) void tree_kernel(
    const unsigned short* __restrict__ WTf, const unsigned short* __restrict__ embb,
    const float* __restrict__ bias, const int* __restrict__ tokens,
    unsigned short* __restrict__ hA, unsigned short* __restrict__ cA,
    unsigned short* __restrict__ hB, unsigned short* __restrict__ cB,
    float* __restrict__ out, uint32* __restrict__ bar)
{
    __shared__ __align__(16) unsigned short cst[128 * 64];   // 16 KB
    __shared__ __align__(16) unsigned short wb[2 * 4096];    // 16 KB

    const int tid  = threadIdx.x;
    const int lane = tid & 63;
    const int w    = tid >> 6;
    const int quad = lane >> 4, col15 = lane & 15;
    const short8v* WTfv = (const short8v*)WTf;

    for (int d = 9; d >= 0; --d) {
        const int n = 1 << d;
        const int nrb = (B_SZ << d) >> 6;        // row-blocks: 2..1024
        const int tiles = nrb * 4;

        const unsigned short *hs, *cs;
        unsigned short *hd, *cd;
        if (d == 9)      { hs = cs = nullptr; hd = hA; cd = cA; }
        else if (d & 1)  { hs = hB; cs = cB; hd = hA; cd = cA; }
        else             { hs = hA; cs = cA; hd = hB; cd = cB; }

        for (int t = blockIdx.x; t < tiles; t += NBLK) {
            int rowblk, jtile;
            if (d >= 2) {                         // nrb >= 8: XCD-affine slicing
                const int s = t & 7, q = t >> 3, sh = d - 2;
                rowblk = (s << sh) + (q & ((1 << sh) - 1));
                jtile  = q >> sh;
            } else {
                rowblk = t >> 2; jtile = t & 3;
            }
            const int rowBase = rowblk * 64;
            if (d == 9)
                leaf_tile(rowBase, jtile, WTfv, embb, bias, tokens, hd, cd,
                          wb, tid, lane, w, quad, col15);
            else
                inner_tile(d, n, rowBase, jtile, WTfv, embb, bias, tokens,
                           hs, cs, hd, cd, out, cst, wb,
                           tid, lane, w, quad, col15);
        }
        if (d > 0) grid_sync(bar);
    }
}

// ---------------------------------------------------------------------------
extern "C" void kernel_launch(void* const* d_in, const int* in_sizes, int n_in,
                              void* d_out, int out_size, void* d_ws, size_t ws_size,
                              hipStream_t stream)
{
    const int*   tokens = (const int*)d_in[0];
    const float* emb    = (const float*)d_in[1];
    const float* Wx     = (const float*)d_in[2];
    const float* Ul     = (const float*)d_in[3];
    const float* Ur     = (const float*)d_in[4];
    const float* bias   = (const float*)d_in[5];
    float* out = (float*)d_out;

    // Workspace: bar 256B | embb 1.05MB | WTf 1.97MB | hA,cA 67.1MB | hB,cB 33.6MB
    const size_t EMB_ELEMS = (size_t)VOCAB * HDIM;
    const size_t WTF_ELEMS = (size_t)80 * 24 * 64 * 8;
    const size_t SLOT_A    = (size_t)512 * B_SZ * HDIM;
    const size_t SLOT_B    = (size_t)256 * B_SZ * HDIM;
    const size_t REQUIRED  = 256 + (EMB_ELEMS + WTF_ELEMS + 2 * (SLOT_A + SLOT_B)) * 2;
    if (ws_size < REQUIRED || d_ws == nullptr) return;   // clean fail, not a fault

    char* ws = (char*)d_ws;
    uint32* bar = (uint32*)ws;
    unsigned short* embb = (unsigned short*)(ws + 256);
    unsigned short* WTf  = embb + EMB_ELEMS;
    unsigned short* hA   = WTf + WTF_ELEMS;
    unsigned short* cA   = hA + SLOT_A;
    unsigned short* hB   = cA + SLOT_A;
    unsigned short* cB   = hB + SLOT_B;

    hipMemsetAsync((void*)bar, 0, 256, stream);          // barrier state (ws is poisoned)
    embb_kernel<<<dim3(256), 256, 0, stream>>>(emb, embb);
    prep_wtf<<<dim3(480), 256, 0, stream>>>(Ul, Ur, Wx, WTf);
    tree_kernel<<<dim3(NBLK), 256, 0, stream>>>(
        WTf, embb, bias, tokens, hA, cA, hB, cB, out, bar);
}

// Round 8
// 657.560 us; speedup vs baseline: 2.9370x; 2.9370x over previous
//
#include <hip/hip_runtime.h>
#include <hip/hip_bf16.h>
#include <math.h>

// Problem constants (from reference)
#define B_SZ   128
#define HDIM   256
#define NG     1280     // 5*H
#define NNODES 1023
#define VOCAB  2048

typedef unsigned int uint32;
typedef short  short8v  __attribute__((ext_vector_type(8)));   // 8 x bf16 (4 VGPR)
typedef float  float4v  __attribute__((ext_vector_type(4)));   // MFMA C/D frag

__device__ __forceinline__ float sigm(float x) {
    return 1.0f / (1.0f + __expf(-x));
}
__device__ __forceinline__ float tanh_fast(float x) {
    return 2.0f / (1.0f + __expf(-2.0f * x)) - 1.0f;
}
__device__ __forceinline__ float bf2f(unsigned short u) {
    return __uint_as_float(((uint32)u) << 16);
}
__device__ __forceinline__ unsigned short f2bf(float f) {
    uint32 x = __float_as_uint(f);
    uint32 r = (x + 0x7FFFu + ((x >> 16) & 1u)) >> 16;   // RNE
    return (unsigned short)r;
}

// ---------------------------------------------------------------------------
// embb = bf16(emb) : 2048 x 256.  1 MB table -> L2-resident gather target.
// ---------------------------------------------------------------------------
__global__ __launch_bounds__(256) void embb_kernel(
    const float* __restrict__ emb, unsigned short* __restrict__ embb)
{
    const int t = blockIdx.x * 256 + threadIdx.x;
    const float4 v0 = *(const float4*)(emb + (size_t)t * 8);
    const float4 v1 = *(const float4*)(emb + (size_t)t * 8 + 4);
    short8v o;
    o[0] = (short)f2bf(v0.x); o[1] = (short)f2bf(v0.y);
    o[2] = (short)f2bf(v0.z); o[3] = (short)f2bf(v0.w);
    o[4] = (short)f2bf(v1.x); o[5] = (short)f2bf(v1.y);
    o[6] = (short)f2bf(v1.z); o[7] = (short)f2bf(v1.w);
    *(short8v*)(embb + (size_t)t * 8) = o;
}

// ---------------------------------------------------------------------------
// WTf: fragment-ready bf16 repack of [Ul;Ur;Wx] (K=768, N=1280) for MFMA B.
// short8 index = (ng*24 + ks)*64 + lane ; lane = q*16 + c
//   holds B[k = ks*32 + q*8 + j][col = ng*16 + c],  j = 0..7
// ---------------------------------------------------------------------------
__global__ __launch_bounds__(256) void prep_wtf(
    const float* __restrict__ Ul, const float* __restrict__ Ur,
    const float* __restrict__ Wx, unsigned short* __restrict__ WTf)
{
    const int t = blockIdx.x * 256 + threadIdx.x;   // 0..122879
    const int l = t & 63;
    const int q = l >> 4, c = l & 15;
    const int ks = (t >> 6) % 24;
    const int ng = t / (24 * 64);                    // 0..79
    const int col = ng * 16 + c;
    const int k = ks * 32 + q * 8;
    const float* src = (k < 256) ? (Ul + (size_t)k * NG + col)
                     : (k < 512) ? (Ur + (size_t)(k - 256) * NG + col)
                                 : (Wx + (size_t)(k - 512) * NG + col);
    short8v v;
    #pragma unroll
    for (int j = 0; j < 8; ++j) v[j] = (short)f2bf(src[(size_t)j * NG]);
    *(short8v*)(WTf + (size_t)t * 8) = v;
}

// ---------------------------------------------------------------------------
// Leaf level (d=9): gates {i,o,u} = x @ Wx + b via MFMA, x = embb[tok].
// Row id r = b*512 + i (row-major state).  512 threads = 8 waves:
// wave w -> row-half rh=w>>2 (32 rows), col-quarter wc=w&3 (16 cols), 3 gates.
// Grid: bid = jt*1024 + rb  (XCD-affine: all jtiles of rb share bid%8).
// ---------------------------------------------------------------------------
__global__ __launch_bounds__(512, 4) void leaf_kernel(
    const unsigned short* __restrict__ WTf, const unsigned short* __restrict__ embb,
    const float* __restrict__ bias, const int* __restrict__ tokens,
    unsigned short* __restrict__ hdst, unsigned short* __restrict__ cdst)
{
    __shared__ __align__(16) unsigned short wb[2 * 4096];   // 16 KB h/c writeback

    const int tid  = threadIdx.x;
    const int lane = tid & 63;
    const int w    = tid >> 6;
    const int rh = w >> 2, wc = w & 3;
    const int quad = lane >> 4, col15 = lane & 15;
    const int bid = blockIdx.x;
    const int rb = bid & 1023, jt = bid >> 10;
    const int rowBase = rb * 64;
    const int jbase   = jt * 64;

    const unsigned short* xp[2];
    #pragma unroll
    for (int rt = 0; rt < 2; ++rt) {
        const int row = rowBase + rh * 32 + rt * 16 + col15;
        const int b = row >> 9, i = row & 511;
        const int tok = tokens[b * NNODES + 511 + i];
        xp[rt] = embb + (size_t)tok * HDIM + quad * 8;
    }
    const short8v* bp[3];
    bp[0] = (const short8v*)WTf + ((size_t)(0 * 16 + jt * 4 + wc) * 24 + 16) * 64 + lane;
    bp[1] = (const short8v*)WTf + ((size_t)(3 * 16 + jt * 4 + wc) * 24 + 16) * 64 + lane;
    bp[2] = (const short8v*)WTf + ((size_t)(4 * 16 + jt * 4 + wc) * 24 + 16) * 64 + lane;

    float4v acc[2][3];
    #pragma unroll
    for (int rt = 0; rt < 2; ++rt)
        #pragma unroll
        for (int gi = 0; gi < 3; ++gi)
            #pragma unroll
            for (int e = 0; e < 4; ++e) acc[rt][gi][e] = 0.0f;

    short8v ab[2][2], bb[2][3];
    #pragma unroll
    for (int rt = 0; rt < 2; ++rt) ab[0][rt] = *(const short8v*)xp[rt];
    #pragma unroll
    for (int gi = 0; gi < 3; ++gi) bb[0][gi] = bp[gi][0];

    #pragma unroll
    for (int ks = 0; ks < 8; ++ks) {
        const int cur = ks & 1, nxt = cur ^ 1;
        if (ks < 7) {
            #pragma unroll
            for (int rt = 0; rt < 2; ++rt)
                ab[nxt][rt] = *(const short8v*)(xp[rt] + (ks + 1) * 32);
            #pragma unroll
            for (int gi = 0; gi < 3; ++gi) bb[nxt][gi] = bp[gi][(size_t)(ks + 1) * 64];
        }
        #pragma unroll
        for (int rt = 0; rt < 2; ++rt)
            #pragma unroll
            for (int gi = 0; gi < 3; ++gi)
                acc[rt][gi] = __builtin_amdgcn_mfma_f32_16x16x32_bf16(
                    ab[cur][rt], bb[cur][gi], acc[rt][gi], 0, 0, 0);
    }

    const int jl = wc * 16 + col15;
    const int j  = jbase + jl;
    const float b_i = bias[j], b_o = bias[768 + j], b_u = bias[1024 + j];
    const int jchunk = jl >> 3, jpos = jl & 7;

    #pragma unroll
    for (int rt = 0; rt < 2; ++rt) {
        #pragma unroll
        for (int reg = 0; reg < 4; ++reg) {
            const int rr = rh * 32 + rt * 16 + quad * 4 + reg;
            const float gi = acc[rt][0][reg] + b_i;
            const float go = acc[rt][1][reg] + b_o;
            const float gu = acc[rt][2][reg] + b_u;
            const float c = sigm(gi) * tanh_fast(gu);
            const float h = sigm(go) * tanh_fast(c);
            const int roff = ((jchunk + 2 * quad) & 7) * 8 + jpos;  // (rr>>2)&3==quad
            wb[rr * 64 + roff]        = f2bf(h);
            wb[4096 + rr * 64 + roff] = f2bf(c);
        }
    }
    __syncthreads();
    #pragma unroll
    for (int k2 = 0; k2 < 2; ++k2) {
        const int c = tid + k2 * 512;                // 0..1023
        const int arr = c >> 9, rr = (c >> 3) & 63, u = c & 7;
        const int ru = (u + 2 * ((rr >> 2) & 3)) & 7;
        const short8v v = *(const short8v*)(wb + (arr * 4096 + rr * 64 + ru * 8));
        unsigned short* dstp = (arr ? cdst : hdst) +
            (size_t)(rowBase + rr) * HDIM + jbase + u * 8;
        *(short8v*)dstp = v;
    }
}

// ---------------------------------------------------------------------------
// Inner level d (8..0): MFMA GEMM [hl|hr|x](Mx768) @ [Ul;Ur;Wx](768x1280) +
// LSTM cell.  Row id r = b*n + i; child rows of r are 2r, 2r+1 (contiguous).
// 512 threads = 8 waves: wave w -> row-half rh (32 rows) x 16 cols x 5 gates
// (acc 40 VGPR/lane -> 4 waves/SIMD, 16 waves/CU: 2x the MLP of round 6).
// Grid: bid = jt*NRB + rb (NRB=2^(d+1)) -> XCD-affine jtile grouping.
// ---------------------------------------------------------------------------
__global__ __launch_bounds__(512, 4) void level_kernel(
    const unsigned short* __restrict__ WTf, const unsigned short* __restrict__ embb,
    const float* __restrict__ bias, const int* __restrict__ tokens,
    const unsigned short* __restrict__ hsrc, const unsigned short* __restrict__ csrc,
    unsigned short* __restrict__ hdst, unsigned short* __restrict__ cdst,
    float* __restrict__ out, const int d)
{
    const int n = 1 << d;

    __shared__ __align__(16) unsigned short cst[128 * 64];   // 16 KB child c
    __shared__ __align__(16) unsigned short wb[2 * 4096];    // 16 KB writeback

    const int tid  = threadIdx.x;
    const int lane = tid & 63;
    const int w    = tid >> 6;
    const int rh = w >> 2, wc = w & 3;
    const int quad = lane >> 4, col15 = lane & 15;
    const int bid = blockIdx.x;
    const int NRBm1 = (2 << d) - 1;            // NRB = 2^(d+1)
    const int rb = bid & NRBm1, jt = bid >> (d + 1);
    const int rowBase = rb * 64;
    const int jbase   = jt * 64;

    const unsigned short* chp[2];
    const unsigned short* xp[2];
    #pragma unroll
    for (int rt = 0; rt < 2; ++rt) {
        const int row = rowBase + rh * 32 + rt * 16 + col15;
        const int b = row >> d, i = row & (n - 1);
        chp[rt] = hsrc + (size_t)(2 * row) * HDIM + quad * 8;
        const int tok = tokens[b * NNODES + (n - 1) + i];
        xp[rt] = embb + (size_t)tok * HDIM + quad * 8;
    }
    const short8v* bp[5];
    #pragma unroll
    for (int g = 0; g < 5; ++g)
        bp[g] = (const short8v*)WTf + ((size_t)(g * 16 + jt * 4 + wc) * 24) * 64 + lane;

    float4v acc[2][5];
    #pragma unroll
    for (int rt = 0; rt < 2; ++rt)
        #pragma unroll
        for (int g = 0; g < 5; ++g)
            #pragma unroll
            for (int e = 0; e < 4; ++e) acc[rt][g][e] = 0.0f;

    short8v ab[2][2], bb[2][5];
    #pragma unroll
    for (int rt = 0; rt < 2; ++rt) ab[0][rt] = *(const short8v*)chp[rt];
    #pragma unroll
    for (int g = 0; g < 5; ++g) bb[0][g] = bp[g][0];

    #pragma unroll
    for (int ks = 0; ks < 24; ++ks) {
        const int cur = ks & 1, nxt = cur ^ 1;
        if (ks < 23) {
            const int kn = ks + 1;
            #pragma unroll
            for (int rt = 0; rt < 2; ++rt) {
                const unsigned short* p =
                    (kn < 8)  ? (chp[rt] + kn * 32)
                  : (kn < 16) ? (chp[rt] + HDIM + (kn - 8) * 32)
                              : (xp[rt] + (kn - 16) * 32);
                ab[nxt][rt] = *(const short8v*)p;
            }
            #pragma unroll
            for (int g = 0; g < 5; ++g) bb[nxt][g] = bp[g][(size_t)kn * 64];
        }
        #pragma unroll
        for (int rt = 0; rt < 2; ++rt)
            #pragma unroll
            for (int g = 0; g < 5; ++g)
                acc[rt][g] = __builtin_amdgcn_mfma_f32_16x16x32_bf16(
                    ab[cur][rt], bb[cur][g], acc[rt][g], 0, 0, 0);
    }

    // ---- Stage child c (contiguous rows 2*rowBase..+128), swizzled ----
    #pragma unroll
    for (int k2 = 0; k2 < 2; ++k2) {
        const int c = tid + k2 * 512;                // 0..1023
        const int rr = c >> 4, side = (c >> 3) & 1, u = c & 7;
        const short8v v = *(const short8v*)(csrc +
            (size_t)(2 * (rowBase + rr) + side) * HDIM + jbase + u * 8);
        const int ru = (u + 2 * ((rr >> 2) & 3)) & 7;
        *(short8v*)(cst + (rr * 128 + side * 64 + ru * 8)) = v;
    }
    __syncthreads();

    // ---- Cell math (C layout: col=lane&15, row=quad*4+reg — verified m89) ----
    const int jl = wc * 16 + col15;
    const int j  = jbase + jl;
    const float b_i  = bias[j],       b_fl = bias[256 + j], b_fr = bias[512 + j];
    const float b_o  = bias[768 + j], b_u  = bias[1024 + j];
    const int jchunk = jl >> 3, jpos = jl & 7;
    float hv[2][4], cv[2][4];
    #pragma unroll
    for (int rt = 0; rt < 2; ++rt) {
        #pragma unroll
        for (int reg = 0; reg < 4; ++reg) {
            const int rr = rh * 32 + rt * 16 + quad * 4 + reg;
            const int roff = ((jchunk + 2 * quad) & 7) * 8 + jpos;  // (rr>>2)&3==quad
            const float gi  = acc[rt][0][reg] + b_i;
            const float gfl = acc[rt][1][reg] + b_fl;
            const float gfr = acc[rt][2][reg] + b_fr;
            const float go  = acc[rt][3][reg] + b_o;
            const float gu  = acc[rt][4][reg] + b_u;
            const float cl  = bf2f(cst[rr * 128 +      roff]);
            const float cr  = bf2f(cst[rr * 128 + 64 + roff]);
            const float ii = sigm(gi), fl = sigm(gfl), fr = sigm(gfr), oo = sigm(go);
            const float uu = tanh_fast(gu);
            const float c = ii * uu + fl * cl + fr * cr;
            const float h = oo * tanh_fast(c);
            cv[rt][reg] = c; hv[rt][reg] = h;
            if (d == 0) out[(size_t)(rowBase + rr) * HDIM + j] = h;  // n==1 -> b=row
        }
    }
    __syncthreads();

    // ---- Writeback h/c via LDS -> coalesced 16B stores ----
    #pragma unroll
    for (int rt = 0; rt < 2; ++rt) {
        #pragma unroll
        for (int reg = 0; reg < 4; ++reg) {
            const int rr = rh * 32 + rt * 16 + quad * 4 + reg;
            const int roff = ((jchunk + 2 * quad) & 7) * 8 + jpos;
            wb[rr * 64 + roff]        = f2bf(hv[rt][reg]);
            wb[4096 + rr * 64 + roff] = f2bf(cv[rt][reg]);
        }
    }
    __syncthreads();
    #pragma unroll
    for (int k2 = 0; k2 < 2; ++k2) {
        const int c = tid + k2 * 512;                // 0..1023
        const int arr = c >> 9, rr = (c >> 3) & 63, u = c & 7;
        const int ru = (u + 2 * ((rr >> 2) & 3)) & 7;
        const short8v v = *(const short8v*)(wb + (arr * 4096 + rr * 64 + ru * 8));
        unsigned short* dstp = (arr ? cdst : hdst) +
            (size_t)(rowBase + rr) * HDIM + jbase + u * 8;
        *(short8v*)dstp = v;
    }
}

// ---------------------------------------------------------------------------
extern "C" void kernel_launch(void* const* d_in, const int* in_sizes, int n_in,
                              void* d_out, int out_size, void* d_ws, size_t ws_size,
                              hipStream_t stream)
{
    const int*   tokens = (const int*)d_in[0];
    const float* emb    = (const float*)d_in[1];
    const float* Wx     = (const float*)d_in[2];
    const float* Ul     = (const float*)d_in[3];
    const float* Ur     = (const float*)d_in[4];
    const float* bias   = (const float*)d_in[5];
    float* out = (float*)d_out;

    // Workspace (bf16): embb 1.05 MB | WTf 1.97 MB | hA,cA 67.1 MB | hB,cB 33.6 MB
    const size_t EMB_ELEMS = (size_t)VOCAB * HDIM;
    const size_t WTF_ELEMS = (size_t)80 * 24 * 64 * 8;
    const size_t SLOT_A    = (size_t)512 * B_SZ * HDIM;
    const size_t SLOT_B    = (size_t)256 * B_SZ * HDIM;
    const size_t REQUIRED  = (EMB_ELEMS + WTF_ELEMS + 2 * (SLOT_A + SLOT_B)) * 2;
    if (ws_size < REQUIRED || d_ws == nullptr) return;   // clean fail, not a fault

    char* ws = (char*)d_ws;
    unsigned short* embb = (unsigned short*)ws;
    unsigned short* WTf  = embb + EMB_ELEMS;
    unsigned short* hA   = WTf + WTF_ELEMS;
    unsigned short* cA   = hA + SLOT_A;
    unsigned short* hB   = cA + SLOT_A;
    unsigned short* cB   = hB + SLOT_B;

    embb_kernel<<<dim3(256), 256, 0, stream>>>(emb, embb);
    prep_wtf<<<dim3(480), 256, 0, stream>>>(Ul, Ur, Wx, WTf);

    // Leaf level d=9 -> slot A (rows r = b*512 + i); 4096 blocks
    leaf_kernel<<<dim3(4096), 512, 0, stream>>>(WTf, embb, bias, tokens, hA, cA);

    // Levels d=8..0
    for (int d = 8; d >= 0; --d) {
        const int NRB = 2 << d;                  // (128<<d)/64
        const bool evenD = ((d & 1) == 0);
        const unsigned short* hs = evenD ? hA : hB;
        const unsigned short* cs = evenD ? cA : cB;
        unsigned short* hd = evenD ? hB : hA;
        unsigned short* cd = evenD ? cB : cA;
        level_kernel<<<dim3(NRB * 4), 512, 0, stream>>>(
            WTf, embb, bias, tokens, hs, cs, hd, cd, out, d);
    }
}

// Round 9
// 503.812 us; speedup vs baseline: 3.8333x; 1.3052x over previous
//
#include <hip/hip_runtime.h>
#include <hip/hip_bf16.h>
#include <math.h>

// Problem constants (from reference)
#define B_SZ   128
#define HDIM   256
#define NG     1280     // 5*H
#define NNODES 1023
#define VOCAB  2048

typedef unsigned int uint32;
typedef short  short8v  __attribute__((ext_vector_type(8)));   // 8 x bf16 (4 VGPR)
typedef float  float4v  __attribute__((ext_vector_type(4)));   // MFMA C/D frag

__device__ __forceinline__ float sigm(float x) {
    return 1.0f / (1.0f + __expf(-x));
}
__device__ __forceinline__ float tanh_fast(float x) {
    return 2.0f / (1.0f + __expf(-2.0f * x)) - 1.0f;
}
__device__ __forceinline__ float bf2f(unsigned short u) {
    return __uint_as_float(((uint32)u) << 16);
}
__device__ __forceinline__ unsigned short f2bf(float f) {
    uint32 x = __float_as_uint(f);
    uint32 r = (x + 0x7FFFu + ((x >> 16) & 1u)) >> 16;   // RNE
    return (unsigned short)r;
}

// ---------------------------------------------------------------------------
// EWb = bf16(emb @ Wx + b) : (2048 x 1280), K=256. fp32 compute, 64x64 tiles.
// ---------------------------------------------------------------------------
__global__ __launch_bounds__(256) void ew_kernel(
    const float* __restrict__ emb, const float* __restrict__ Wx,
    const float* __restrict__ bias, unsigned short* __restrict__ EWb)
{
    __shared__ float As[16][76];
    __shared__ float Bs[16][72];

    const int tid = threadIdx.x;
    const int tx = tid & 15, ty = tid >> 4;
    const int rowBase = blockIdx.x * 64;
    const int colBase = blockIdx.y * 64;

    const int a_rr = tid >> 2, a_kq = tid & 3;
    const int b_kk = tid >> 4, b_c4 = tid & 15;

    float acc[4][4] = {};

    for (int kb = 0; kb < 256; kb += 16) {
        float4 av = *(const float4*)(emb + (size_t)(rowBase + a_rr) * 256 + kb + a_kq * 4);
        float4 bv = *(const float4*)(Wx + (size_t)(kb + b_kk) * NG + colBase + b_c4 * 4);
        __syncthreads();
        As[a_kq * 4 + 0][a_rr] = av.x;
        As[a_kq * 4 + 1][a_rr] = av.y;
        As[a_kq * 4 + 2][a_rr] = av.z;
        As[a_kq * 4 + 3][a_rr] = av.w;
        *(float4*)&Bs[b_kk][b_c4 * 4] = bv;
        __syncthreads();
        #pragma unroll
        for (int k = 0; k < 16; ++k) {
            float4 a = *(const float4*)&As[k][ty * 4];
            float4 b = *(const float4*)&Bs[k][tx * 4];
            acc[0][0] += a.x * b.x; acc[0][1] += a.x * b.y; acc[0][2] += a.x * b.z; acc[0][3] += a.x * b.w;
            acc[1][0] += a.y * b.x; acc[1][1] += a.y * b.y; acc[1][2] += a.y * b.z; acc[1][3] += a.y * b.w;
            acc[2][0] += a.z * b.x; acc[2][1] += a.z * b.y; acc[2][2] += a.z * b.z; acc[2][3] += a.z * b.w;
            acc[3][0] += a.w * b.x; acc[3][1] += a.w * b.y; acc[3][2] += a.w * b.z; acc[3][3] += a.w * b.w;
        }
    }

    #pragma unroll
    for (int u = 0; u < 4; ++u) {
        const int row = rowBase + ty * 4 + u;
        const int col = colBase + tx * 4;
        float4 bb = *(const float4*)(bias + col);
        ushort4 ov;
        ov.x = f2bf(acc[u][0] + bb.x);
        ov.y = f2bf(acc[u][1] + bb.y);
        ov.z = f2bf(acc[u][2] + bb.z);
        ov.w = f2bf(acc[u][3] + bb.w);
        *(ushort4*)(EWb + (size_t)row * NG + col) = ov;
    }
}

// ---------------------------------------------------------------------------
// embb = bf16(emb) : 2048 x 256.  1 MB table -> L2-resident gather target.
// ---------------------------------------------------------------------------
__global__ __launch_bounds__(256) void embb_kernel(
    const float* __restrict__ emb, unsigned short* __restrict__ embb)
{
    const int t = blockIdx.x * 256 + threadIdx.x;
    const float4 v0 = *(const float4*)(emb + (size_t)t * 8);
    const float4 v1 = *(const float4*)(emb + (size_t)t * 8 + 4);
    short8v o;
    o[0] = (short)f2bf(v0.x); o[1] = (short)f2bf(v0.y);
    o[2] = (short)f2bf(v0.z); o[3] = (short)f2bf(v0.w);
    o[4] = (short)f2bf(v1.x); o[5] = (short)f2bf(v1.y);
    o[6] = (short)f2bf(v1.z); o[7] = (short)f2bf(v1.w);
    *(short8v*)(embb + (size_t)t * 8) = o;
}

// ---------------------------------------------------------------------------
// WTf: fragment-ready bf16 repack of [Ul;Ur;Wx] (K=768, N=1280) for MFMA B.
// short8 index = (ng*24 + ks)*64 + lane ; lane = q*16 + c
//   holds B[k = ks*32 + q*8 + j][col = ng*16 + c],  j = 0..7
// Levels use ks 0..15 ([Ul;Ur]); the leaf uses ks 16..23 (Wx).
// ---------------------------------------------------------------------------
__global__ __launch_bounds__(256) void prep_wtf(
    const float* __restrict__ Ul, const float* __restrict__ Ur,
    const float* __restrict__ Wx, unsigned short* __restrict__ WTf)
{
    const int t = blockIdx.x * 256 + threadIdx.x;   // 0..122879
    const int l = t & 63;
    const int q = l >> 4, c = l & 15;
    const int ks = (t >> 6) % 24;
    const int ng = t / (24 * 64);                    // 0..79
    const int col = ng * 16 + c;
    const int k = ks * 32 + q * 8;
    const float* src = (k < 256) ? (Ul + (size_t)k * NG + col)
                     : (k < 512) ? (Ur + (size_t)(k - 256) * NG + col)
                                 : (Wx + (size_t)(k - 512) * NG + col);
    short8v v;
    #pragma unroll
    for (int j = 0; j < 8; ++j) v[j] = (short)f2bf(src[(size_t)j * NG]);
    *(short8v*)(WTf + (size_t)t * 8) = v;
}

// ---------------------------------------------------------------------------
// Leaf (d=9): gates {i,o,u} = x @ Wx + b via MFMA, x = embb[tok] (L2-resident).
// Row-major state: row r = b*512 + i.  512 thr = 8 waves (rh, wc).
// ---------------------------------------------------------------------------
__global__ __launch_bounds__(512, 4) void leaf_kernel(
    const unsigned short* __restrict__ WTf, const unsigned short* __restrict__ embb,
    const float* __restrict__ bias, const int* __restrict__ tokens,
    unsigned short* __restrict__ hdst, unsigned short* __restrict__ cdst)
{
    __shared__ __align__(16) unsigned short wb[2 * 4096];   // 16 KB h/c writeback

    const int tid  = threadIdx.x;
    const int lane = tid & 63;
    const int w    = tid >> 6;
    const int rh = w >> 2, wc = w & 3;
    const int quad = lane >> 4, col15 = lane & 15;
    const int jt = blockIdx.x;                 // 0..3 (fastest)
    const int rowBase = blockIdx.y * 64;
    const int jbase   = jt * 64;

    const unsigned short* ap[2];
    #pragma unroll
    for (int rt = 0; rt < 2; ++rt) {
        const int row = rowBase + rh * 32 + rt * 16 + col15;
        const int b = row >> 9, i = row & 511;
        const int tok = tokens[b * NNODES + 511 + i];
        ap[rt] = embb + (size_t)tok * HDIM + quad * 8;
    }
    const short8v* bp[3];
    bp[0] = (const short8v*)WTf + ((size_t)(0 * 16 + jt * 4 + wc) * 24 + 16) * 64 + lane;
    bp[1] = (const short8v*)WTf + ((size_t)(3 * 16 + jt * 4 + wc) * 24 + 16) * 64 + lane;
    bp[2] = (const short8v*)WTf + ((size_t)(4 * 16 + jt * 4 + wc) * 24 + 16) * 64 + lane;

    float4v acc[2][3];
    #pragma unroll
    for (int rt = 0; rt < 2; ++rt)
        #pragma unroll
        for (int gi = 0; gi < 3; ++gi)
            #pragma unroll
            for (int e = 0; e < 4; ++e) acc[rt][gi][e] = 0.0f;

    short8v ab[2][2];
    ab[0][0] = *(const short8v*)ap[0];
    ab[0][1] = *(const short8v*)ap[1];

    #pragma unroll
    for (int ks = 0; ks < 8; ++ks) {
        const int cur = ks & 1, nxt = cur ^ 1;
        short8v bf[3];
        #pragma unroll
        for (int gi = 0; gi < 3; ++gi) bf[gi] = bp[gi][(size_t)ks * 64];
        if (ks < 7) {
            ab[nxt][0] = *(const short8v*)(ap[0] + (ks + 1) * 32);
            ab[nxt][1] = *(const short8v*)(ap[1] + (ks + 1) * 32);
        }
        #pragma unroll
        for (int rt = 0; rt < 2; ++rt)
            #pragma unroll
            for (int gi = 0; gi < 3; ++gi)
                acc[rt][gi] = __builtin_amdgcn_mfma_f32_16x16x32_bf16(
                    ab[cur][rt], bf[gi], acc[rt][gi], 0, 0, 0);
    }

    const int jl = wc * 16 + col15;
    const int j  = jbase + jl;
    const float b_i = bias[j], b_o = bias[768 + j], b_u = bias[1024 + j];
    const int jchunk = jl >> 3, jpos = jl & 7;

    #pragma unroll
    for (int rt = 0; rt < 2; ++rt) {
        #pragma unroll
        for (int reg = 0; reg < 4; ++reg) {
            const int rr = rh * 32 + rt * 16 + quad * 4 + reg;
            const float gi = acc[rt][0][reg] + b_i;
            const float go = acc[rt][1][reg] + b_o;
            const float gu = acc[rt][2][reg] + b_u;
            const float c = sigm(gi) * tanh_fast(gu);
            const float h = sigm(go) * tanh_fast(c);
            const int roff = ((jchunk + 2 * quad) & 7) * 8 + jpos;  // (rr>>2)&3==quad
            wb[rr * 64 + roff]        = f2bf(h);
            wb[4096 + rr * 64 + roff] = f2bf(c);
        }
    }
    __syncthreads();
    #pragma unroll
    for (int k2 = 0; k2 < 2; ++k2) {
        const int c = tid + k2 * 512;                // 0..1023
        const int arr = c >> 9, rr = (c >> 3) & 63, u = c & 7;
        const int ru = (u + 2 * ((rr >> 2) & 3)) & 7;
        const short8v v = *(const short8v*)(wb + (arr * 4096 + rr * 64 + ru * 8));
        unsigned short* dstp = (arr ? cdst : hdst) +
            (size_t)(rowBase + rr) * HDIM + jbase + u * 8;
        *(short8v*)dstp = v;
    }
}

// ---------------------------------------------------------------------------
// Inner level d (8..0): MFMA GEMM [hl|hr](Mx512) @ [Ul;Ur](512x1280) + EW
// gather + LSTM cell.  Row-major state: children of row r are rows 2r,2r+1
// -> [hl|hr] is ONE contiguous 1KB span at hsrc + 2r*256.
// 512 thr = 8 waves (rh: 32-row half, wc: 16-col quarter), acc 40 VGPR/lane;
// A dist-1 register dbuf, B single-buffered (R8 postmortem: B-dbuf's +40
// VGPRs caused scratch spills at the 128-reg/16-wave cap).
// Epilogue: EWb rows + child c staged via LDS 16B vector loads (R5, proven).
// Grid: jt fastest (R5's mapping; R8's jt-major destroyed temporal L2 reuse).
// ---------------------------------------------------------------------------
__global__ __launch_bounds__(512, 4) void level_kernel(
    const unsigned short* __restrict__ WTf, const unsigned short* __restrict__ EWb,
    const int* __restrict__ tokens,
    const unsigned short* __restrict__ hsrc, const unsigned short* __restrict__ csrc,
    unsigned short* __restrict__ hdst, unsigned short* __restrict__ cdst,
    float* __restrict__ out, const int d)
{
    const int n = 1 << d;

    __shared__ int toks[64];
    __shared__ __align__(16) unsigned short ews[5 * 64 * 64];  // 40 KB (reused for wb)
    __shared__ __align__(16) unsigned short cst[128 * 64];     // 16 KB child c

    const int tid  = threadIdx.x;
    const int lane = tid & 63;
    const int w    = tid >> 6;
    const int rh = w >> 2, wc = w & 3;
    const int quad = lane >> 4, col15 = lane & 15;
    const int jt = blockIdx.x;                 // 0..3 (fastest)
    const int rowBase = blockIdx.y * 64;
    const int jbase   = jt * 64;

    if (tid < 64) {
        const int row = rowBase + tid;
        const int b = row >> d, i = row & (n - 1);
        toks[tid] = tokens[b * NNODES + (n - 1) + i];
    }

    // ---- A pointers: [h(2r)|h(2r+1)] contiguous, k-offset = ks*32 ----
    const unsigned short* ap[2];
    #pragma unroll
    for (int rt = 0; rt < 2; ++rt) {
        const int row = rowBase + rh * 32 + rt * 16 + col15;
        ap[rt] = hsrc + (size_t)(2 * row) * HDIM + quad * 8;
    }
    const short8v* bp[5];
    #pragma unroll
    for (int g = 0; g < 5; ++g)
        bp[g] = (const short8v*)WTf + ((size_t)(g * 16 + jt * 4 + wc) * 24) * 64 + lane;

    float4v acc[2][5];
    #pragma unroll
    for (int rt = 0; rt < 2; ++rt)
        #pragma unroll
        for (int g = 0; g < 5; ++g)
            #pragma unroll
            for (int e = 0; e < 4; ++e) acc[rt][g][e] = 0.0f;

    short8v ab[2][2];
    ab[0][0] = *(const short8v*)ap[0];
    ab[0][1] = *(const short8v*)ap[1];

    #pragma unroll
    for (int ks = 0; ks < 16; ++ks) {
        const int cur = ks & 1, nxt = cur ^ 1;
        short8v bf[5];
        #pragma unroll
        for (int g = 0; g < 5; ++g) bf[g] = bp[g][(size_t)ks * 64];
        if (ks < 15) {
            ab[nxt][0] = *(const short8v*)(ap[0] + (ks + 1) * 32);
            ab[nxt][1] = *(const short8v*)(ap[1] + (ks + 1) * 32);
        }
        #pragma unroll
        for (int rt = 0; rt < 2; ++rt)
            #pragma unroll
            for (int g = 0; g < 5; ++g)
                acc[rt][g] = __builtin_amdgcn_mfma_f32_16x16x32_bf16(
                    ab[cur][rt], bf[g], acc[rt][g], 0, 0, 0);
    }

    __syncthreads();    // toks visible; LDS free

    // ---- Stage EWb rows: 5 gates x 64 rows x 8 chunks(16B) = 2560; 5/thread.
    #pragma unroll
    for (int k2 = 0; k2 < 5; ++k2) {
        const int c = tid + k2 * 512;
        const uint32 row = (uint32)c / 40u;
        const int rem = c - (int)row * 40;
        const int g = rem >> 3, u = rem & 7;
        const int tok = toks[row];
        const short8v v = *(const short8v*)(EWb + (size_t)tok * NG + g * 256 + jbase + u * 8);
        const int ru = (u + 2 * ((row >> 2) & 3)) & 7;
        *(short8v*)(ews + ((g * 64 + row) * 64 + ru * 8)) = v;
    }
    // ---- Stage child c: contiguous rows 2*rowBase..+128; 1024 chunks, 2/thr.
    #pragma unroll
    for (int k2 = 0; k2 < 2; ++k2) {
        const int c = tid + k2 * 512;
        const int rr = c >> 4, side = (c >> 3) & 1, u = c & 7;
        const short8v v = *(const short8v*)(csrc +
            (size_t)(2 * (rowBase + rr) + side) * HDIM + jbase + u * 8);
        const int ru = (u + 2 * ((rr >> 2) & 3)) & 7;
        *(short8v*)(cst + (rr * 128 + side * 64 + ru * 8)) = v;
    }
    __syncthreads();

    // ---- Cell math (C layout: col=lane&15, row=quad*4+reg — verified m89) ----
    const int jl = wc * 16 + col15;
    const int j  = jbase + jl;
    const int jchunk = jl >> 3, jpos = jl & 7;
    float hv[2][4], cv[2][4];
    #pragma unroll
    for (int rt = 0; rt < 2; ++rt) {
        #pragma unroll
        for (int reg = 0; reg < 4; ++reg) {
            const int rr = rh * 32 + rt * 16 + quad * 4 + reg;
            const int roff = ((jchunk + 2 * quad) & 7) * 8 + jpos;  // (rr>>2)&3==quad
            const float gi  = acc[rt][0][reg] + bf2f(ews[(0 * 64 + rr) * 64 + roff]);
            const float gfl = acc[rt][1][reg] + bf2f(ews[(1 * 64 + rr) * 64 + roff]);
            const float gfr = acc[rt][2][reg] + bf2f(ews[(2 * 64 + rr) * 64 + roff]);
            const float go  = acc[rt][3][reg] + bf2f(ews[(3 * 64 + rr) * 64 + roff]);
            const float gu  = acc[rt][4][reg] + bf2f(ews[(4 * 64 + rr) * 64 + roff]);
            const float cl  = bf2f(cst[rr * 128 +      roff]);
            const float cr  = bf2f(cst[rr * 128 + 64 + roff]);
            const float ii = sigm(gi), fl = sigm(gfl), fr = sigm(gfr), oo = sigm(go);
            const float uu = tanh_fast(gu);
            const float c = ii * uu + fl * cl + fr * cr;
            const float h = oo * tanh_fast(c);
            cv[rt][reg] = c; hv[rt][reg] = h;
            if (d == 0) out[(size_t)(rowBase + rr) * HDIM + j] = h;  // n==1 -> b=row
        }
    }
    __syncthreads();    // ews/cst reads done; reuse ews for writeback

    #pragma unroll
    for (int rt = 0; rt < 2; ++rt) {
        #pragma unroll
        for (int reg = 0; reg < 4; ++reg) {
            const int rr = rh * 32 + rt * 16 + quad * 4 + reg;
            const int roff = ((jchunk + 2 * quad) & 7) * 8 + jpos;
            ews[rr * 64 + roff]        = f2bf(hv[rt][reg]);
            ews[4096 + rr * 64 + roff] = f2bf(cv[rt][reg]);
        }
    }
    __syncthreads();
    #pragma unroll
    for (int k2 = 0; k2 < 2; ++k2) {
        const int c = tid + k2 * 512;                // 0..1023
        const int arr = c >> 9, rr = (c >> 3) & 63, u = c & 7;
        const int ru = (u + 2 * ((rr >> 2) & 3)) & 7;
        const short8v v = *(const short8v*)(ews + (arr * 4096 + rr * 64 + ru * 8));
        unsigned short* dstp = (arr ? cdst : hdst) +
            (size_t)(rowBase + rr) * HDIM + jbase + u * 8;
        *(short8v*)dstp = v;
    }
}

// ---------------------------------------------------------------------------
extern "C" void kernel_launch(void* const* d_in, const int* in_sizes, int n_in,
                              void* d_out, int out_size, void* d_ws, size_t ws_size,
                              hipStream_t stream)
{
    const int*   tokens = (const int*)d_in[0];
    const float* emb    = (const float*)d_in[1];
    const float* Wx     = (const float*)d_in[2];
    const float* Ul     = (const float*)d_in[3];
    const float* Ur     = (const float*)d_in[4];
    const float* bias   = (const float*)d_in[5];
    float* out = (float*)d_out;

    // Workspace (bf16): EWb 5.24 | embb 1.05 | WTf 1.97 | hA,cA 67.1 | hB,cB 33.6
    // total ~109 MB (< round-1's known-good 111.2 MB)
    const size_t EW_ELEMS  = (size_t)VOCAB * NG;
    const size_t EMB_ELEMS = (size_t)VOCAB * HDIM;
    const size_t WTF_ELEMS = (size_t)80 * 24 * 64 * 8;
    const size_t SLOT_A    = (size_t)512 * B_SZ * HDIM;
    const size_t SLOT_B    = (size_t)256 * B_SZ * HDIM;
    const size_t REQUIRED  = (EW_ELEMS + EMB_ELEMS + WTF_ELEMS + 2 * (SLOT_A + SLOT_B)) * 2;
    if (ws_size < REQUIRED || d_ws == nullptr) return;   // clean fail, not a fault

    char* ws = (char*)d_ws;
    unsigned short* EWb  = (unsigned short*)ws;
    unsigned short* embb = EWb + EW_ELEMS;
    unsigned short* WTf  = embb + EMB_ELEMS;
    unsigned short* hA   = WTf + WTF_ELEMS;
    unsigned short* cA   = hA + SLOT_A;
    unsigned short* hB   = cA + SLOT_A;
    unsigned short* cB   = hB + SLOT_B;

    ew_kernel<<<dim3(VOCAB / 64, NG / 64), 256, 0, stream>>>(emb, Wx, bias, EWb);
    embb_kernel<<<dim3(256), 256, 0, stream>>>(emb, embb);
    prep_wtf<<<dim3(480), 256, 0, stream>>>(Ul, Ur, Wx, WTf);

    // Leaf d=9 -> slot A (row-major r = b*512 + i)
    leaf_kernel<<<dim3(4, 1024), 512, 0, stream>>>(WTf, embb, bias, tokens, hA, cA);

    // Levels d=8..0 (jt fastest in grid.x -> col-tiles of a row-block adjacent)
    for (int d = 8; d >= 0; --d) {
        const int NRB = 2 << d;
        const bool evenD = ((d & 1) == 0);
        const unsigned short* hs = evenD ? hA : hB;
        const unsigned short* cs = evenD ? cA : cB;
        unsigned short* hd = evenD ? hB : hA;
        unsigned short* cd = evenD ? cB : cA;
        level_kernel<<<dim3(4, NRB), 512, 0, stream>>>(
            WTf, EWb, tokens, hs, cs, hd, cd, out, d);
    }
}

// Round 10
// 412.859 us; speedup vs baseline: 4.6778x; 1.2203x over previous
//
#include <hip/hip_runtime.h>
#include <hip/hip_bf16.h>
#include <math.h>

// Problem constants (from reference)
#define B_SZ   128
#define HDIM   256
#define NG     1280     // 5*H
#define NNODES 1023
#define VOCAB  2048

typedef unsigned int uint32;
typedef short  short8v  __attribute__((ext_vector_type(8)));   // 8 x bf16 (4 VGPR)
typedef float  float4v  __attribute__((ext_vector_type(4)));   // MFMA C/D frag

__device__ __forceinline__ float sigm(float x) {
    return 1.0f / (1.0f + __expf(-x));
}
__device__ __forceinline__ float tanh_fast(float x) {
    return 2.0f / (1.0f + __expf(-2.0f * x)) - 1.0f;
}
__device__ __forceinline__ float bf2f(unsigned short u) {
    return __uint_as_float(((uint32)u) << 16);
}
__device__ __forceinline__ unsigned short f2bf(float f) {
    uint32 x = __float_as_uint(f);
    uint32 r = (x + 0x7FFFu + ((x >> 16) & 1u)) >> 16;   // RNE
    return (unsigned short)r;
}

// Async 16B/lane global->LDS DMA. LDS dest = wave-uniform base + lane*16
// (per-lane scatter allowed on the GLOBAL side only). [learn_hip m97/m104]
__device__ __forceinline__ void dma16(const unsigned short* gptr, unsigned short* lptr) {
    __builtin_amdgcn_global_load_lds(
        (const __attribute__((address_space(1))) void*)gptr,
        (__attribute__((address_space(3))) void*)lptr, 16, 0, 0);
}

// ---------------------------------------------------------------------------
// EWb = bf16(emb @ Wx + b) : (2048 x 1280), K=256. fp32 compute, 64x64 tiles.
// ---------------------------------------------------------------------------
__global__ __launch_bounds__(256) void ew_kernel(
    const float* __restrict__ emb, const float* __restrict__ Wx,
    const float* __restrict__ bias, unsigned short* __restrict__ EWb)
{
    __shared__ float As[16][76];
    __shared__ float Bs[16][72];

    const int tid = threadIdx.x;
    const int tx = tid & 15, ty = tid >> 4;
    const int rowBase = blockIdx.x * 64;
    const int colBase = blockIdx.y * 64;

    const int a_rr = tid >> 2, a_kq = tid & 3;
    const int b_kk = tid >> 4, b_c4 = tid & 15;

    float acc[4][4] = {};

    for (int kb = 0; kb < 256; kb += 16) {
        float4 av = *(const float4*)(emb + (size_t)(rowBase + a_rr) * 256 + kb + a_kq * 4);
        float4 bv = *(const float4*)(Wx + (size_t)(kb + b_kk) * NG + colBase + b_c4 * 4);
        __syncthreads();
        As[a_kq * 4 + 0][a_rr] = av.x;
        As[a_kq * 4 + 1][a_rr] = av.y;
        As[a_kq * 4 + 2][a_rr] = av.z;
        As[a_kq * 4 + 3][a_rr] = av.w;
        *(float4*)&Bs[b_kk][b_c4 * 4] = bv;
        __syncthreads();
        #pragma unroll
        for (int k = 0; k < 16; ++k) {
            float4 a = *(const float4*)&As[k][ty * 4];
            float4 b = *(const float4*)&Bs[k][tx * 4];
            acc[0][0] += a.x * b.x; acc[0][1] += a.x * b.y; acc[0][2] += a.x * b.z; acc[0][3] += a.x * b.w;
            acc[1][0] += a.y * b.x; acc[1][1] += a.y * b.y; acc[1][2] += a.y * b.z; acc[1][3] += a.y * b.w;
            acc[2][0] += a.z * b.x; acc[2][1] += a.z * b.y; acc[2][2] += a.z * b.z; acc[2][3] += a.z * b.w;
            acc[3][0] += a.w * b.x; acc[3][1] += a.w * b.y; acc[3][2] += a.w * b.z; acc[3][3] += a.w * b.w;
        }
    }

    #pragma unroll
    for (int u = 0; u < 4; ++u) {
        const int row = rowBase + ty * 4 + u;
        const int col = colBase + tx * 4;
        float4 bb = *(const float4*)(bias + col);
        ushort4 ov;
        ov.x = f2bf(acc[u][0] + bb.x);
        ov.y = f2bf(acc[u][1] + bb.y);
        ov.z = f2bf(acc[u][2] + bb.z);
        ov.w = f2bf(acc[u][3] + bb.w);
        *(ushort4*)(EWb + (size_t)row * NG + col) = ov;
    }
}

// ---------------------------------------------------------------------------
// embb = bf16(emb) : 2048 x 256.  1 MB table -> L2-resident leaf A operand.
// ---------------------------------------------------------------------------
__global__ __launch_bounds__(256) void embb_kernel(
    const float* __restrict__ emb, unsigned short* __restrict__ embb)
{
    const int t = blockIdx.x * 256 + threadIdx.x;
    const float4 v0 = *(const float4*)(emb + (size_t)t * 8);
    const float4 v1 = *(const float4*)(emb + (size_t)t * 8 + 4);
    short8v o;
    o[0] = (short)f2bf(v0.x); o[1] = (short)f2bf(v0.y);
    o[2] = (short)f2bf(v0.z); o[3] = (short)f2bf(v0.w);
    o[4] = (short)f2bf(v1.x); o[5] = (short)f2bf(v1.y);
    o[6] = (short)f2bf(v1.z); o[7] = (short)f2bf(v1.w);
    *(short8v*)(embb + (size_t)t * 8) = o;
}

// ---------------------------------------------------------------------------
// WTf: fragment-ready bf16 repack of [Ul;Ur;Wx] (K=768, N=1280) for MFMA B.
// short8 index = (ng*24 + ks)*64 + lane ; lane = q*16 + c
//   holds B[k = ks*32 + q*8 + j][col = ng*16 + c],  j = 0..7
// Levels use ks 0..15 ([Ul;Ur]); the leaf uses ks 16..23 (Wx).
// ---------------------------------------------------------------------------
__global__ __launch_bounds__(256) void prep_wtf(
    const float* __restrict__ Ul, const float* __restrict__ Ur,
    const float* __restrict__ Wx, unsigned short* __restrict__ WTf)
{
    const int t = blockIdx.x * 256 + threadIdx.x;   // 0..122879
    const int l = t & 63;
    const int q = l >> 4, c = l & 15;
    const int ks = (t >> 6) % 24;
    const int ng = t / (24 * 64);                    // 0..79
    const int col = ng * 16 + c;
    const int k = ks * 32 + q * 8;
    const float* src = (k < 256) ? (Ul + (size_t)k * NG + col)
                     : (k < 512) ? (Ur + (size_t)(k - 256) * NG + col)
                                 : (Wx + (size_t)(k - 512) * NG + col);
    short8v v;
    #pragma unroll
    for (int j = 0; j < 8; ++j) v[j] = (short)f2bf(src[(size_t)j * NG]);
    *(short8v*)(WTf + (size_t)t * 8) = v;
}

// ---------------------------------------------------------------------------
// Leaf (d=9): gates {i,o,u} = x @ Wx + b, x = embb[tok].  Async-LDS A staging
// (m97 skeleton), BK=64, 4 steps.  512 thr = 8 waves: rh=w>>2 (32 rows),
// wc=w&3 (16 cols); staging role (sub_st=w&1, rt_st=w>>1).
// ---------------------------------------------------------------------------
__global__ __launch_bounds__(512, 4) void leaf_kernel(
    const unsigned short* __restrict__ WTf, const unsigned short* __restrict__ embb,
    const float* __restrict__ bias, const int* __restrict__ tokens,
    unsigned short* __restrict__ hdst, unsigned short* __restrict__ cdst)
{
    __shared__ __align__(16) unsigned short Ab[2][4096];   // 2 x 8 KB A dbuf
    __shared__ __align__(16) unsigned short wb[2 * 4096];  // 16 KB h/c writeback

    const int tid  = threadIdx.x;
    const int lane = tid & 63;
    const int w    = tid >> 6;
    const int rh = w >> 2, wc = w & 3;
    const int quad = lane >> 4, col15 = lane & 15;
    const int jt = blockIdx.x;                 // 0..3 (fastest)
    const int rowBase = blockIdx.y * 64;
    const int jbase   = jt * 64;

    // Staging: wave w stages chunk (sub=w&1, rt=w>>1); lane -> row rt*16+col15
    const int sub_st = w & 1, rt_st = w >> 1;
    const int srow = rowBase + rt_st * 16 + col15;
    const int sb = srow >> 9, si = srow & 511;
    const int stok = tokens[sb * NNODES + 511 + si];
    const unsigned short* agp = embb + (size_t)stok * HDIM + sub_st * 32 + quad * 8;
    unsigned short* const ldst = &Ab[0][0] + (sub_st * 4 + rt_st) * 512;  // + buf*4096

    // B: gates {i,o,u} = ng rows {0,3,4}; Wx section = ks32 16..23
    const short8v* WTfv = (const short8v*)WTf;
    uint32 boff[3];
    boff[0] = ((0 * 16 + jt * 4 + wc) * 24 + 16) * 64 + lane;
    boff[1] = ((3 * 16 + jt * 4 + wc) * 24 + 16) * 64 + lane;
    boff[2] = ((4 * 16 + jt * 4 + wc) * 24 + 16) * 64 + lane;

    float4v acc[2][3];
    #pragma unroll
    for (int rt = 0; rt < 2; ++rt)
        #pragma unroll
        for (int gi = 0; gi < 3; ++gi)
            #pragma unroll
            for (int e = 0; e < 4; ++e) acc[rt][gi][e] = 0.0f;

    dma16(agp, ldst);                          // step 0 -> buf 0
    __syncthreads();

    #pragma unroll
    for (int s = 0; s < 4; ++s) {
        if (s < 3) dma16(agp + (s + 1) * 64, ldst + ((s + 1) & 1) * 4096);

        short8v bf[2][3];
        #pragma unroll
        for (int sub = 0; sub < 2; ++sub)
            #pragma unroll
            for (int gi = 0; gi < 3; ++gi)
                bf[sub][gi] = WTfv[boff[gi] + (s * 2 + sub) * 64];

        short8v af[2][2];
        #pragma unroll
        for (int sub = 0; sub < 2; ++sub)
            #pragma unroll
            for (int rt = 0; rt < 2; ++rt)
                af[sub][rt] = *(const short8v*)&Ab[s & 1][(sub * 4 + rh * 2 + rt) * 512 + lane * 8];

        #pragma unroll
        for (int sub = 0; sub < 2; ++sub)
            #pragma unroll
            for (int rt = 0; rt < 2; ++rt)
                #pragma unroll
                for (int gi = 0; gi < 3; ++gi)
                    acc[rt][gi] = __builtin_amdgcn_mfma_f32_16x16x32_bf16(
                        af[sub][rt], bf[sub][gi], acc[rt][gi], 0, 0, 0);
        __syncthreads();
    }

    // Cell + writeback (C layout: col=lane&15, row=quad*4+reg — verified m89)
    const int jl = wc * 16 + col15;
    const int j  = jbase + jl;
    const float b_i = bias[j], b_o = bias[768 + j], b_u = bias[1024 + j];
    const int jchunk = jl >> 3, jpos = jl & 7;

    #pragma unroll
    for (int rt = 0; rt < 2; ++rt) {
        #pragma unroll
        for (int reg = 0; reg < 4; ++reg) {
            const int rr = rh * 32 + rt * 16 + quad * 4 + reg;
            const float gi = acc[rt][0][reg] + b_i;
            const float go = acc[rt][1][reg] + b_o;
            const float gu = acc[rt][2][reg] + b_u;
            const float c = sigm(gi) * tanh_fast(gu);
            const float h = sigm(go) * tanh_fast(c);
            const int roff = ((jchunk + 2 * quad) & 7) * 8 + jpos;  // (rr>>2)&3==quad
            wb[rr * 64 + roff]        = f2bf(h);
            wb[4096 + rr * 64 + roff] = f2bf(c);
        }
    }
    __syncthreads();
    #pragma unroll
    for (int k2 = 0; k2 < 2; ++k2) {
        const int c = tid + k2 * 512;                // 0..1023
        const int arr = c >> 9, rr = (c >> 3) & 63, u = c & 7;
        const int ru = (u + 2 * ((rr >> 2) & 3)) & 7;
        const short8v v = *(const short8v*)(wb + (arr * 4096 + rr * 64 + ru * 8));
        unsigned short* dstp = (arr ? cdst : hdst) +
            (size_t)(rowBase + rr) * HDIM + jbase + u * 8;
        *(short8v*)dstp = v;
    }
}

// ---------------------------------------------------------------------------
// Inner level d (8..0): MFMA GEMM [hl|hr](Mx512) @ [Ul;Ur](512x1280) + EW
// gather + LSTM cell.  R9 postmortem: time invariant under occupancy =>
// per-CU vector-path outstanding-capacity bound.  This version:
//  - A staged ONCE per block via async global_load_lds (kills 4x wave dup,
//    zero VGPR cost), BK=64 double-buffered, one barrier/step (m97 skeleton).
//  - B register-direct from frag-ready WTf (2 sub-frags x 5 gates per step).
//  - Epilogue EWb/child-c gathered by async DMA spread over steps 2..5 into
//    linear LDS -> latency absorbed by K-loop compute.
// ---------------------------------------------------------------------------
__global__ __launch_bounds__(512, 4) void level_kernel(
    const unsigned short* __restrict__ WTf, const unsigned short* __restrict__ EWb,
    const int* __restrict__ tokens,
    const unsigned short* __restrict__ hsrc, const unsigned short* __restrict__ csrc,
    unsigned short* __restrict__ hdst, unsigned short* __restrict__ cdst,
    float* __restrict__ out, const int d)
{
    const int n = 1 << d;

    __shared__ __align__(16) unsigned short Ab[2][4096];     // 2 x 8 KB A dbuf
    __shared__ __align__(16) unsigned short ews[2560 * 8];   // 40 KB EW gather (linear; reused as wb)
    __shared__ __align__(16) unsigned short cst[1024 * 8];   // 16 KB child c (linear)

    const int tid  = threadIdx.x;
    const int lane = tid & 63;
    const int w    = tid >> 6;
    const int rh = w >> 2, wc = w & 3;
    const int quad = lane >> 4, col15 = lane & 15;
    const int jt = blockIdx.x;                 // 0..3 (fastest)
    const int rowBase = blockIdx.y * 64;
    const int jbase   = jt * 64;

    // ---- A staging: wave w stages chunk (sub=w&1, rt=w>>1) of each step ----
    const int sub_st = w & 1, rt_st = w >> 1;
    const int srow = rowBase + rt_st * 16 + col15;
    const unsigned short* agp = hsrc + (size_t)(2 * srow) * HDIM + sub_st * 32 + quad * 8;
    unsigned short* const ldst = &Ab[0][0] + (sub_st * 4 + rt_st) * 512;  // + buf*4096

    // ---- B frag offsets (short8v units): gate g, ks32 = s*2+sub in 0..15 ----
    const short8v* WTfv = (const short8v*)WTf;
    uint32 boff[5];
    #pragma unroll
    for (int g = 0; g < 5; ++g)
        boff[g] = ((g * 16 + jt * 4 + wc) * 24) * 64 + lane;

    float4v acc[2][5];
    #pragma unroll
    for (int rt = 0; rt < 2; ++rt)
        #pragma unroll
        for (int g = 0; g < 5; ++g)
            #pragma unroll
            for (int e = 0; e < 4; ++e) acc[rt][g][e] = 0.0f;

    dma16(agp, ldst);                          // step 0 -> buf 0
    __syncthreads();

    #pragma unroll
    for (int s = 0; s < 8; ++s) {
        if (s < 7) dma16(agp + (s + 1) * 64, ldst + ((s + 1) & 1) * 4096);

        // Epilogue-operand DMAs, spread across steps 2..5 (latency absorbed):
        // EWb: 2560 16B chunks, iters k=0..4 at s=2,2,3,3,4; cst: k=0,1 at s=4,5.
        if (s >= 2 && s <= 5) {
            const int base_iter = (s - 2) * 2;           // 0,2,4,6
            #pragma unroll
            for (int t2 = 0; t2 < 2; ++t2) {
                const int it = base_iter + t2;           // 0..7
                if (it < 5) {                            // EWb chunks
                    const int c = tid + it * 512;
                    const uint32 row = (uint32)c / 40u;
                    const int rem = c - (int)row * 40;
                    const int g = rem >> 3, u = rem & 7;
                    const int grow = rowBase + (int)row;
                    const int tok = tokens[(grow >> d) * NNODES + (n - 1) + (grow & (n - 1))];
                    dma16(EWb + (size_t)tok * NG + g * 256 + jbase + u * 8,
                          ews + ((size_t)w * 64 + (size_t)it * 512) * 8);
                } else if (it < 7) {                     // cst chunks
                    const int k2 = it - 5;
                    const int c = tid + k2 * 512;
                    const int rr = c >> 4, side = (c >> 3) & 1, u = c & 7;
                    dma16(csrc + (size_t)(2 * (rowBase + rr) + side) * HDIM + jbase + u * 8,
                          cst + ((size_t)w * 64 + (size_t)k2 * 512) * 8);
                }
            }
        }

        short8v bf[2][5];
        #pragma unroll
        for (int sub = 0; sub < 2; ++sub)
            #pragma unroll
            for (int g = 0; g < 5; ++g)
                bf[sub][g] = WTfv[boff[g] + (s * 2 + sub) * 64];

        short8v af[2][2];
        #pragma unroll
        for (int sub = 0; sub < 2; ++sub)
            #pragma unroll
            for (int rt = 0; rt < 2; ++rt)
                af[sub][rt] = *(const short8v*)&Ab[s & 1][(sub * 4 + rh * 2 + rt) * 512 + lane * 8];

        #pragma unroll
        for (int sub = 0; sub < 2; ++sub)
            #pragma unroll
            for (int rt = 0; rt < 2; ++rt)
                #pragma unroll
                for (int g = 0; g < 5; ++g)
                    acc[rt][g] = __builtin_amdgcn_mfma_f32_16x16x32_bf16(
                        af[sub][rt], bf[sub][g], acc[rt][g], 0, 0, 0);
        __syncthreads();
    }

    // ---- Cell math from LDS (linear layouts; C layout col=lane&15,
    //      row=quad*4+reg — verified m89) ----
    const int jl = wc * 16 + col15;
    const int j  = jbase + jl;
    float hv[2][4], cv[2][4];
    #pragma unroll
    for (int rt = 0; rt < 2; ++rt) {
        #pragma unroll
        for (int reg = 0; reg < 4; ++reg) {
            const int rr = rh * 32 + rt * 16 + quad * 4 + reg;
            const float gi  = acc[rt][0][reg] + bf2f(ews[rr * 320 +       jl]);
            const float gfl = acc[rt][1][reg] + bf2f(ews[rr * 320 +  64 + jl]);
            const float gfr = acc[rt][2][reg] + bf2f(ews[rr * 320 + 128 + jl]);
            const float go  = acc[rt][3][reg] + bf2f(ews[rr * 320 + 192 + jl]);
            const float gu  = acc[rt][4][reg] + bf2f(ews[rr * 320 + 256 + jl]);
            const float cl  = bf2f(cst[rr * 128 +      jl]);
            const float cr  = bf2f(cst[rr * 128 + 64 + jl]);
            const float ii = sigm(gi), fl = sigm(gfl), fr = sigm(gfr), oo = sigm(go);
            const float uu = tanh_fast(gu);
            const float c = ii * uu + fl * cl + fr * cr;
            const float h = oo * tanh_fast(c);
            cv[rt][reg] = c; hv[rt][reg] = h;
            if (d == 0) out[(size_t)(rowBase + rr) * HDIM + j] = h;  // n==1 -> b=row
        }
    }
    __syncthreads();    // ews/cst reads done; reuse ews region for writeback

    const int jchunk = jl >> 3, jpos = jl & 7;
    #pragma unroll
    for (int rt = 0; rt < 2; ++rt) {
        #pragma unroll
        for (int reg = 0; reg < 4; ++reg) {
            const int rr = rh * 32 + rt * 16 + quad * 4 + reg;
            const int roff = ((jchunk + 2 * quad) & 7) * 8 + jpos;  // (rr>>2)&3==quad
            ews[rr * 64 + roff]        = f2bf(hv[rt][reg]);
            ews[4096 + rr * 64 + roff] = f2bf(cv[rt][reg]);
        }
    }
    __syncthreads();
    #pragma unroll
    for (int k2 = 0; k2 < 2; ++k2) {
        const int c = tid + k2 * 512;                // 0..1023
        const int arr = c >> 9, rr = (c >> 3) & 63, u = c & 7;
        const int ru = (u + 2 * ((rr >> 2) & 3)) & 7;
        const short8v v = *(const short8v*)(ews + (arr * 4096 + rr * 64 + ru * 8));
        unsigned short* dstp = (arr ? cdst : hdst) +
            (size_t)(rowBase + rr) * HDIM + jbase + u * 8;
        *(short8v*)dstp = v;
    }
}

// ---------------------------------------------------------------------------
extern "C" void kernel_launch(void* const* d_in, const int* in_sizes, int n_in,
                              void* d_out, int out_size, void* d_ws, size_t ws_size,
                              hipStream_t stream)
{
    const int*   tokens = (const int*)d_in[0];
    const float* emb    = (const float*)d_in[1];
    const float* Wx     = (const float*)d_in[2];
    const float* Ul     = (const float*)d_in[3];
    const float* Ur     = (const float*)d_in[4];
    const float* bias   = (const float*)d_in[5];
    float* out = (float*)d_out;

    // Workspace (bf16): EWb 5.24 | embb 1.05 | WTf 1.97 | hA,cA 67.1 | hB,cB 33.6
    // total ~109 MB (known-good footprint)
    const size_t EW_ELEMS  = (size_t)VOCAB * NG;
    const size_t EMB_ELEMS = (size_t)VOCAB * HDIM;
    const size_t WTF_ELEMS = (size_t)80 * 24 * 64 * 8;
    const size_t SLOT_A    = (size_t)512 * B_SZ * HDIM;
    const size_t SLOT_B    = (size_t)256 * B_SZ * HDIM;
    const size_t REQUIRED  = (EW_ELEMS + EMB_ELEMS + WTF_ELEMS + 2 * (SLOT_A + SLOT_B)) * 2;
    if (ws_size < REQUIRED || d_ws == nullptr) return;   // clean fail, not a fault

    char* ws = (char*)d_ws;
    unsigned short* EWb  = (unsigned short*)ws;
    unsigned short* embb = EWb + EW_ELEMS;
    unsigned short* WTf  = embb + EMB_ELEMS;
    unsigned short* hA   = WTf + WTF_ELEMS;
    unsigned short* cA   = hA + SLOT_A;
    unsigned short* hB   = cA + SLOT_A;
    unsigned short* cB   = hB + SLOT_B;

    ew_kernel<<<dim3(VOCAB / 64, NG / 64), 256, 0, stream>>>(emb, Wx, bias, EWb);
    embb_kernel<<<dim3(256), 256, 0, stream>>>(emb, embb);
    prep_wtf<<<dim3(480), 256, 0, stream>>>(Ul, Ur, Wx, WTf);

    // Leaf d=9 -> slot A (row-major r = b*512 + i)
    leaf_kernel<<<dim3(4, 1024), 512, 0, stream>>>(WTf, embb, bias, tokens, hA, cA);

    // Levels d=8..0 (jt fastest in grid.x -> col-tiles of a row-block adjacent)
    for (int d = 8; d >= 0; --d) {
        const int NRB = 2 << d;
        const bool evenD = ((d & 1) == 0);
        const unsigned short* hs = evenD ? hA : hB;
        const unsigned short* cs = evenD ? cA : cB;
        unsigned short* hd = evenD ? hB : hA;
        unsigned short* cd = evenD ? cB : cA;
        level_kernel<<<dim3(4, NRB), 512, 0, stream>>>(
            WTf, EWb, tokens, hs, cs, hd, cd, out, d);
    }
}

// Round 11
// 385.319 us; speedup vs baseline: 5.0121x; 1.0715x over previous
//
#include <hip/hip_runtime.h>
#include <hip/hip_bf16.h>
#include <math.h>

// Problem constants (from reference)
#define B_SZ   128
#define HDIM   256
#define NG     1280     // 5*H
#define NNODES 1023
#define VOCAB  2048

typedef unsigned int uint32;
typedef short  short8v  __attribute__((ext_vector_type(8)));   // 8 x bf16 (4 VGPR)
typedef float  float4v  __attribute__((ext_vector_type(4)));   // MFMA C/D frag

__device__ __forceinline__ float sigm(float x) {
    return 1.0f / (1.0f + __expf(-x));
}
__device__ __forceinline__ float tanh_fast(float x) {
    return 2.0f / (1.0f + __expf(-2.0f * x)) - 1.0f;
}
__device__ __forceinline__ float bf2f(unsigned short u) {
    return __uint_as_float(((uint32)u) << 16);
}
__device__ __forceinline__ unsigned short f2bf(float f) {
    uint32 x = __float_as_uint(f);
    uint32 r = (x + 0x7FFFu + ((x >> 16) & 1u)) >> 16;   // RNE
    return (unsigned short)r;
}

// Async 16B/lane global->LDS DMA. LDS dest = wave-uniform base + lane*16.
__device__ __forceinline__ void dma16(const unsigned short* gptr, unsigned short* lptr) {
    __builtin_amdgcn_global_load_lds(
        (const __attribute__((address_space(1))) void*)gptr,
        (__attribute__((address_space(3))) void*)lptr, 16, 0, 0);
}

// ---------------------------------------------------------------------------
// EWb = bf16(emb @ Wx + b) : (2048 x 1280), K=256. fp32 compute, 64x64 tiles.
// ---------------------------------------------------------------------------
__global__ __launch_bounds__(256) void ew_kernel(
    const float* __restrict__ emb, const float* __restrict__ Wx,
    const float* __restrict__ bias, unsigned short* __restrict__ EWb)
{
    __shared__ float As[16][76];
    __shared__ float Bs[16][72];

    const int tid = threadIdx.x;
    const int tx = tid & 15, ty = tid >> 4;
    const int rowBase = blockIdx.x * 64;
    const int colBase = blockIdx.y * 64;

    const int a_rr = tid >> 2, a_kq = tid & 3;
    const int b_kk = tid >> 4, b_c4 = tid & 15;

    float acc[4][4] = {};

    for (int kb = 0; kb < 256; kb += 16) {
        float4 av = *(const float4*)(emb + (size_t)(rowBase + a_rr) * 256 + kb + a_kq * 4);
        float4 bv = *(const float4*)(Wx + (size_t)(kb + b_kk) * NG + colBase + b_c4 * 4);
        __syncthreads();
        As[a_kq * 4 + 0][a_rr] = av.x;
        As[a_kq * 4 + 1][a_rr] = av.y;
        As[a_kq * 4 + 2][a_rr] = av.z;
        As[a_kq * 4 + 3][a_rr] = av.w;
        *(float4*)&Bs[b_kk][b_c4 * 4] = bv;
        __syncthreads();
        #pragma unroll
        for (int k = 0; k < 16; ++k) {
            float4 a = *(const float4*)&As[k][ty * 4];
            float4 b = *(const float4*)&Bs[k][tx * 4];
            acc[0][0] += a.x * b.x; acc[0][1] += a.x * b.y; acc[0][2] += a.x * b.z; acc[0][3] += a.x * b.w;
            acc[1][0] += a.y * b.x; acc[1][1] += a.y * b.y; acc[1][2] += a.y * b.z; acc[1][3] += a.y * b.w;
            acc[2][0] += a.z * b.x; acc[2][1] += a.z * b.y; acc[2][2] += a.z * b.z; acc[2][3] += a.z * b.w;
            acc[3][0] += a.w * b.x; acc[3][1] += a.w * b.y; acc[3][2] += a.w * b.z; acc[3][3] += a.w * b.w;
        }
    }

    #pragma unroll
    for (int u = 0; u < 4; ++u) {
        const int row = rowBase + ty * 4 + u;
        const int col = colBase + tx * 4;
        float4 bb = *(const float4*)(bias + col);
        ushort4 ov;
        ov.x = f2bf(acc[u][0] + bb.x);
        ov.y = f2bf(acc[u][1] + bb.y);
        ov.z = f2bf(acc[u][2] + bb.z);
        ov.w = f2bf(acc[u][3] + bb.w);
        *(ushort4*)(EWb + (size_t)row * NG + col) = ov;
    }
}

// ---------------------------------------------------------------------------
// embb = bf16(emb) : 2048 x 256.  1 MB table -> L2-resident leaf A operand.
// ---------------------------------------------------------------------------
__global__ __launch_bounds__(256) void embb_kernel(
    const float* __restrict__ emb, unsigned short* __restrict__ embb)
{
    const int t = blockIdx.x * 256 + threadIdx.x;
    const float4 v0 = *(const float4*)(emb + (size_t)t * 8);
    const float4 v1 = *(const float4*)(emb + (size_t)t * 8 + 4);
    short8v o;
    o[0] = (short)f2bf(v0.x); o[1] = (short)f2bf(v0.y);
    o[2] = (short)f2bf(v0.z); o[3] = (short)f2bf(v0.w);
    o[4] = (short)f2bf(v1.x); o[5] = (short)f2bf(v1.y);
    o[6] = (short)f2bf(v1.z); o[7] = (short)f2bf(v1.w);
    *(short8v*)(embb + (size_t)t * 8) = o;
}

// ---------------------------------------------------------------------------
// WTf: fragment-ready bf16 repack of [Ul;Ur;Wx] (K=768, N=1280) for MFMA B.
// short8 index = (ng*24 + ks)*64 + lane ; lane = q*16 + c
//   holds B[k = ks*32 + q*8 + j][col = ng*16 + c],  j = 0..7
// Levels use ks 0..15 ([Ul;Ur]); the leaf uses ks 16..23 (Wx).
// ---------------------------------------------------------------------------
__global__ __launch_bounds__(256) void prep_wtf(
    const float* __restrict__ Ul, const float* __restrict__ Ur,
    const float* __restrict__ Wx, unsigned short* __restrict__ WTf)
{
    const int t = blockIdx.x * 256 + threadIdx.x;   // 0..122879
    const int l = t & 63;
    const int q = l >> 4, c = l & 15;
    const int ks = (t >> 6) % 24;
    const int ng = t / (24 * 64);                    // 0..79
    const int col = ng * 16 + c;
    const int k = ks * 32 + q * 8;
    const float* src = (k < 256) ? (Ul + (size_t)k * NG + col)
                     : (k < 512) ? (Ur + (size_t)(k - 256) * NG + col)
                                 : (Wx + (size_t)(k - 512) * NG + col);
    short8v v;
    #pragma unroll
    for (int j = 0; j < 8; ++j) v[j] = (short)f2bf(src[(size_t)j * NG]);
    *(short8v*)(WTf + (size_t)t * 8) = v;
}

// ---------------------------------------------------------------------------
// Leaf (d=9): gates {i,o,u} = x @ Wx + b, x = embb[tok].  256 thr = 4 waves;
// wave w = col-tile w (16 cols), ALL 64 rows (rt=4), 3 gates -> B loaded once
// per block (no wave duplication).  A via async-LDS DMA, BK=64, 4 steps.
// ---------------------------------------------------------------------------
__global__ __launch_bounds__(256, 2) void leaf_kernel(
    const unsigned short* __restrict__ WTf, const unsigned short* __restrict__ embb,
    const float* __restrict__ bias, const int* __restrict__ tokens,
    unsigned short* __restrict__ hdst, unsigned short* __restrict__ cdst)
{
    __shared__ __align__(16) unsigned short Ab[2][4096];   // 2 x 8 KB A dbuf
    __shared__ __align__(16) unsigned short wb[2 * 4096];  // 16 KB h/c writeback

    const int tid  = threadIdx.x;
    const int lane = tid & 63;
    const int w    = tid >> 6;                  // 0..3 = col-tile
    const int quad = lane >> 4, col15 = lane & 15;
    const int jt = blockIdx.x;                  // 0..3 (fastest)
    const int rowBase = blockIdx.y * 64;
    const int jbase   = jt * 64;

    // A staging: 8 chunks/step (ch = sub*4 + rt); wave w stages ch = 2w, 2w+1
    const unsigned short* agp[2];
    unsigned short* ldst[2];
    #pragma unroll
    for (int t = 0; t < 2; ++t) {
        const int ch = 2 * w + t, sub = ch >> 2, rt = ch & 3;
        const int srow = rowBase + rt * 16 + col15;
        const int sb = srow >> 9, si = srow & 511;
        const int stok = tokens[sb * NNODES + 511 + si];
        agp[t]  = embb + (size_t)stok * HDIM + sub * 32 + quad * 8;
        ldst[t] = &Ab[0][0] + ch * 512;
    }

    const short8v* WTfv = (const short8v*)WTf;
    uint32 boff[3];
    boff[0] = ((0 * 16 + jt * 4 + w) * 24 + 16) * 64 + lane;
    boff[1] = ((3 * 16 + jt * 4 + w) * 24 + 16) * 64 + lane;
    boff[2] = ((4 * 16 + jt * 4 + w) * 24 + 16) * 64 + lane;

    float4v acc[4][3];
    #pragma unroll
    for (int rt = 0; rt < 4; ++rt)
        #pragma unroll
        for (int gi = 0; gi < 3; ++gi)
            #pragma unroll
            for (int e = 0; e < 4; ++e) acc[rt][gi][e] = 0.0f;

    dma16(agp[0], ldst[0]); dma16(agp[1], ldst[1]);
    __syncthreads();

    #pragma unroll
    for (int s = 0; s < 4; ++s) {
        if (s < 3) {
            dma16(agp[0] + (s + 1) * 64, ldst[0] + ((s + 1) & 1) * 4096);
            dma16(agp[1] + (s + 1) * 64, ldst[1] + ((s + 1) & 1) * 4096);
        }
        #pragma unroll
        for (int sub = 0; sub < 2; ++sub) {
            short8v bf[3];
            #pragma unroll
            for (int gi = 0; gi < 3; ++gi) bf[gi] = WTfv[boff[gi] + (s * 2 + sub) * 64];
            #pragma unroll
            for (int rt = 0; rt < 4; ++rt) {
                const short8v af = *(const short8v*)&Ab[s & 1][(sub * 4 + rt) * 512 + lane * 8];
                #pragma unroll
                for (int gi = 0; gi < 3; ++gi)
                    acc[rt][gi] = __builtin_amdgcn_mfma_f32_16x16x32_bf16(
                        af, bf[gi], acc[rt][gi], 0, 0, 0);
            }
        }
        __syncthreads();
    }

    // Cell + writeback (C layout: col=lane&15, row=quad*4+reg — verified m89)
    const int jl = w * 16 + col15;
    const int j  = jbase + jl;
    const float b_i = bias[j], b_o = bias[768 + j], b_u = bias[1024 + j];
    const int jchunk = jl >> 3, jpos = jl & 7;

    #pragma unroll
    for (int rt = 0; rt < 4; ++rt) {
        #pragma unroll
        for (int reg = 0; reg < 4; ++reg) {
            const int rr = rt * 16 + quad * 4 + reg;
            const float gi = acc[rt][0][reg] + b_i;
            const float go = acc[rt][1][reg] + b_o;
            const float gu = acc[rt][2][reg] + b_u;
            const float c = sigm(gi) * tanh_fast(gu);
            const float h = sigm(go) * tanh_fast(c);
            const int roff = ((jchunk + 2 * quad) & 7) * 8 + jpos;  // (rr>>2)&3==quad
            wb[rr * 64 + roff]        = f2bf(h);
            wb[4096 + rr * 64 + roff] = f2bf(c);
        }
    }
    __syncthreads();
    #pragma unroll
    for (int k2 = 0; k2 < 4; ++k2) {
        const int c = tid + k2 * 256;                // 0..1023
        const int arr = c >> 9, rr = (c >> 3) & 63, u = c & 7;
        const int ru = (u + 2 * ((rr >> 2) & 3)) & 7;
        const short8v v = *(const short8v*)(wb + (arr * 4096 + rr * 64 + ru * 8));
        unsigned short* dstp = (arr ? cdst : hdst) +
            (size_t)(rowBase + rr) * HDIM + jbase + u * 8;
        *(short8v*)dstp = v;
    }
}

// ---------------------------------------------------------------------------
// Inner level d (8..0): MFMA GEMM [hl|hr](Mx512) @ [Ul;Ur](512x1280) + EW
// gather + LSTM cell.  R10 postmortem: time == vector-path bytes / 27 B/cyc/CU
// and B frags were 81% of bytes with 2x wave duplication.  This version:
// 256 thr = 4 waves; wave w = col-tile w, ALL 64 rows (rt=4, acc 80), 5 gates
// -> each B frag loaded exactly once per block (reused 4x in-register).
// A via async-LDS DMA (BK=64 dbuf); EWb/child-c DMA'd during the K-loop.
// ---------------------------------------------------------------------------
__global__ __launch_bounds__(256, 2) void level_kernel(
    const unsigned short* __restrict__ WTf, const unsigned short* __restrict__ EWb,
    const int* __restrict__ tokens,
    const unsigned short* __restrict__ hsrc, const unsigned short* __restrict__ csrc,
    unsigned short* __restrict__ hdst, unsigned short* __restrict__ cdst,
    float* __restrict__ out, const int d)
{
    const int n = 1 << d;

    __shared__ __align__(16) unsigned short Ab[2][4096];     // 2 x 8 KB A dbuf
    __shared__ __align__(16) unsigned short ews[2560 * 8];   // 40 KB EW gather (reused as wb)
    __shared__ __align__(16) unsigned short cst[1024 * 8];   // 16 KB child c

    const int tid  = threadIdx.x;
    const int lane = tid & 63;
    const int w    = tid >> 6;                  // 0..3 = col-tile
    const int quad = lane >> 4, col15 = lane & 15;
    const int jt = blockIdx.x;                  // 0..3 (fastest)
    const int rowBase = blockIdx.y * 64;
    const int jbase   = jt * 64;

    // ---- A staging: 8 chunks/step (ch = sub*4 + rt); wave w: ch = 2w, 2w+1 ----
    const unsigned short* agp[2];
    unsigned short* ldst[2];
    #pragma unroll
    for (int t = 0; t < 2; ++t) {
        const int ch = 2 * w + t, sub = ch >> 2, rt = ch & 3;
        const int srow = rowBase + rt * 16 + col15;
        agp[t]  = hsrc + (size_t)(2 * srow) * HDIM + sub * 32 + quad * 8;
        ldst[t] = &Ab[0][0] + ch * 512;
    }

    const short8v* WTfv = (const short8v*)WTf;
    uint32 boff[5];
    #pragma unroll
    for (int g = 0; g < 5; ++g)
        boff[g] = ((g * 16 + jt * 4 + w) * 24) * 64 + lane;

    float4v acc[4][5];
    #pragma unroll
    for (int rt = 0; rt < 4; ++rt)
        #pragma unroll
        for (int g = 0; g < 5; ++g)
            #pragma unroll
            for (int e = 0; e < 4; ++e) acc[rt][g][e] = 0.0f;

    dma16(agp[0], ldst[0]); dma16(agp[1], ldst[1]);
    __syncthreads();

    #pragma unroll
    for (int s = 0; s < 8; ++s) {
        if (s < 7) {
            dma16(agp[0] + (s + 1) * 64, ldst[0] + ((s + 1) & 1) * 4096);
            dma16(agp[1] + (s + 1) * 64, ldst[1] + ((s + 1) & 1) * 4096);
        }

        // EWb DMAs (2560 chunks, it=0..9) spread over steps 2..6;
        // child-c DMAs (1024 chunks, k2=0..3) over steps 5..6.
        if (s >= 2 && s <= 6) {
            #pragma unroll
            for (int t2 = 0; t2 < 2; ++t2) {
                const int it = (s - 2) * 2 + t2;         // 0..9
                const int c = tid + it * 256;
                const uint32 row = (uint32)c / 40u;
                const int rem = c - (int)row * 40;
                const int g = rem >> 3, u = rem & 7;
                const int grow = rowBase + (int)row;
                const int tok = tokens[(grow >> d) * NNODES + (n - 1) + (grow & (n - 1))];
                dma16(EWb + (size_t)tok * NG + g * 256 + jbase + u * 8,
                      ews + ((size_t)it * 256 + w * 64) * 8);
            }
            if (s >= 5) {
                #pragma unroll
                for (int t2 = 0; t2 < 2; ++t2) {
                    const int k2 = (s - 5) * 2 + t2;     // 0..3
                    const int c = tid + k2 * 256;
                    const int rr = c >> 4, side = (c >> 3) & 1, u = c & 7;
                    dma16(csrc + (size_t)(2 * (rowBase + rr) + side) * HDIM + jbase + u * 8,
                          cst + ((size_t)k2 * 256 + w * 64) * 8);
                }
            }
        }

        #pragma unroll
        for (int sub = 0; sub < 2; ++sub) {
            short8v bf[5];
            #pragma unroll
            for (int g = 0; g < 5; ++g) bf[g] = WTfv[boff[g] + (s * 2 + sub) * 64];
            #pragma unroll
            for (int rt = 0; rt < 4; ++rt) {
                const short8v af = *(const short8v*)&Ab[s & 1][(sub * 4 + rt) * 512 + lane * 8];
                #pragma unroll
                for (int g = 0; g < 5; ++g)
                    acc[rt][g] = __builtin_amdgcn_mfma_f32_16x16x32_bf16(
                        af, bf[g], acc[rt][g], 0, 0, 0);
            }
        }
        __syncthreads();
    }

    // ---- Cell math from LDS (C layout col=lane&15, row=quad*4+reg) ----
    const int jl = w * 16 + col15;
    const int j  = jbase + jl;
    float hv[4][4], cv[4][4];
    #pragma unroll
    for (int rt = 0; rt < 4; ++rt) {
        #pragma unroll
        for (int reg = 0; reg < 4; ++reg) {
            const int rr = rt * 16 + quad * 4 + reg;
            const float gi  = acc[rt][0][reg] + bf2f(ews[rr * 320 +       jl]);
            const float gfl = acc[rt][1][reg] + bf2f(ews[rr * 320 +  64 + jl]);
            const float gfr = acc[rt][2][reg] + bf2f(ews[rr * 320 + 128 + jl]);
            const float go  = acc[rt][3][reg] + bf2f(ews[rr * 320 + 192 + jl]);
            const float gu  = acc[rt][4][reg] + bf2f(ews[rr * 320 + 256 + jl]);
            const float cl  = bf2f(cst[rr * 128 +      jl]);
            const float cr  = bf2f(cst[rr * 128 + 64 + jl]);
            const float ii = sigm(gi), fl = sigm(gfl), fr = sigm(gfr), oo = sigm(go);
            const float uu = tanh_fast(gu);
            const float c = ii * uu + fl * cl + fr * cr;
            const float h = oo * tanh_fast(c);
            cv[rt][reg] = c; hv[rt][reg] = h;
            if (d == 0) out[(size_t)(rowBase + rr) * HDIM + j] = h;  // n==1 -> b=row
        }
    }
    __syncthreads();    // ews/cst reads done; reuse ews region for writeback

    const int jchunk = jl >> 3, jpos = jl & 7;
    #pragma unroll
    for (int rt = 0; rt < 4; ++rt) {
        #pragma unroll
        for (int reg = 0; reg < 4; ++reg) {
            const int rr = rt * 16 + quad * 4 + reg;
            const int roff = ((jchunk + 2 * quad) & 7) * 8 + jpos;  // (rr>>2)&3==quad
            ews[rr * 64 + roff]        = f2bf(hv[rt][reg]);
            ews[4096 + rr * 64 + roff] = f2bf(cv[rt][reg]);
        }
    }
    __syncthreads();
    #pragma unroll
    for (int k2 = 0; k2 < 4; ++k2) {
        const int c = tid + k2 * 256;                // 0..1023
        const int arr = c >> 9, rr = (c >> 3) & 63, u = c & 7;
        const int ru = (u + 2 * ((rr >> 2) & 3)) & 7;
        const short8v v = *(const short8v*)(ews + (arr * 4096 + rr * 64 + ru * 8));
        unsigned short* dstp = (arr ? cdst : hdst) +
            (size_t)(rowBase + rr) * HDIM + jbase + u * 8;
        *(short8v*)dstp = v;
    }
}

// ---------------------------------------------------------------------------
extern "C" void kernel_launch(void* const* d_in, const int* in_sizes, int n_in,
                              void* d_out, int out_size, void* d_ws, size_t ws_size,
                              hipStream_t stream)
{
    const int*   tokens = (const int*)d_in[0];
    const float* emb    = (const float*)d_in[1];
    const float* Wx     = (const float*)d_in[2];
    const float* Ul     = (const float*)d_in[3];
    const float* Ur     = (const float*)d_in[4];
    const float* bias   = (const float*)d_in[5];
    float* out = (float*)d_out;

    // Workspace (bf16): EWb 5.24 | embb 1.05 | WTf 1.97 | hA,cA 67.1 | hB,cB 33.6
    const size_t EW_ELEMS  = (size_t)VOCAB * NG;
    const size_t EMB_ELEMS = (size_t)VOCAB * HDIM;
    const size_t WTF_ELEMS = (size_t)80 * 24 * 64 * 8;
    const size_t SLOT_A    = (size_t)512 * B_SZ * HDIM;
    const size_t SLOT_B    = (size_t)256 * B_SZ * HDIM;
    const size_t REQUIRED  = (EW_ELEMS + EMB_ELEMS + WTF_ELEMS + 2 * (SLOT_A + SLOT_B)) * 2;
    if (ws_size < REQUIRED || d_ws == nullptr) return;   // clean fail, not a fault

    char* ws = (char*)d_ws;
    unsigned short* EWb  = (unsigned short*)ws;
    unsigned short* embb = EWb + EW_ELEMS;
    unsigned short* WTf  = embb + EMB_ELEMS;
    unsigned short* hA   = WTf + WTF_ELEMS;
    unsigned short* cA   = hA + SLOT_A;
    unsigned short* hB   = cA + SLOT_A;
    unsigned short* cB   = hB + SLOT_B;

    ew_kernel<<<dim3(VOCAB / 64, NG / 64), 256, 0, stream>>>(emb, Wx, bias, EWb);
    embb_kernel<<<dim3(256), 256, 0, stream>>>(emb, embb);
    prep_wtf<<<dim3(480), 256, 0, stream>>>(Ul, Ur, Wx, WTf);

    // Leaf d=9 -> slot A (row-major r = b*512 + i)
    leaf_kernel<<<dim3(4, 1024), 256, 0, stream>>>(WTf, embb, bias, tokens, hA, cA);

    // Levels d=8..0 (jt fastest in grid.x -> col-tiles of a row-block adjacent)
    for (int d = 8; d >= 0; --d) {
        const int NRB = 2 << d;
        const bool evenD = ((d & 1) == 0);
        const unsigned short* hs = evenD ? hA : hB;
        const unsigned short* cs = evenD ? cA : cB;
        unsigned short* hd = evenD ? hB : hA;
        unsigned short* cd = evenD ? cB : cA;
        level_kernel<<<dim3(4, NRB), 256, 0, stream>>>(
            WTf, EWb, tokens, hs, cs, hd, cd, out, d);
    }
}